// Round 13
// baseline (1272.783 us; speedup 1.0000x reference)
//
#include <hip/hip_runtime.h>
#include <hip/hip_bf16.h>
#include <cstddef>

#define NB  4
#define QN  900
#define DM  256
#define HH  8
#define HD  32
#define PP  4
#define HBg 200
#define WBg 200
#define FFD 512
#define NV  (HBg*WBg)   // 40000 bev cells
#define RPB 4           // deform: queries (rows) per block
#define MT  3600        // total rows
#define REPEAT 8        // DIAGNOSTIC: inner-repeat amplification (idempotent kernels)

typedef __hip_bfloat16 bf16;
typedef __attribute__((ext_vector_type(8))) short short8;
typedef __attribute__((ext_vector_type(4))) float floatx4;

__device__ __forceinline__ float bf2f(bf16 x){ return __bfloat162float(x); }
__device__ __forceinline__ unsigned short f2bu(float f){
  bf16 h = __float2bfloat16(f);
  return *(unsigned short*)&h;
}

// ---------------- K0: fused transpose+convert of all GEMM weights + Woff/Wattn ----------------
__global__ void __launch_bounds__(256) cvtAll(
    const float* __restrict__ Wq, const float* __restrict__ Wk,
    const float* __restrict__ Wv, const float* __restrict__ Wo,
    const float* __restrict__ Wval, const float* __restrict__ Wdo,
    const float* __restrict__ W1, const float* __restrict__ W2,
    const float* __restrict__ Woff, const float* __restrict__ Wattn,
    bf16* __restrict__ WqkT, bf16* __restrict__ WvT, bf16* __restrict__ WoT,
    bf16* __restrict__ WvalT, bf16* __restrict__ WdoT,
    bf16* __restrict__ W1T, bf16* __restrict__ W2T,
    bf16* __restrict__ Woffb, bf16* __restrict__ Wattnb){
  int b = blockIdx.x;
  if (b >= 640){
    int i = (b - 640)*256 + threadIdx.x;
    if (i < 16384) Woffb[i] = __float2bfloat16(Woff[i]);
    else if (i < 24576) Wattnb[i - 16384] = __float2bfloat16(Wattn[i - 16384]);
    return;
  }
  const float* S; bf16* D; int K, N, tile;
  if      (b <  64){ S=Wq;   D=WqkT;        K=256; N=256; tile=b; }
  else if (b < 128){ S=Wk;   D=WqkT+65536;  K=256; N=256; tile=b-64; }
  else if (b < 192){ S=Wv;   D=WvT;         K=256; N=256; tile=b-128; }
  else if (b < 256){ S=Wo;   D=WoT;         K=256; N=256; tile=b-192; }
  else if (b < 320){ S=Wval; D=WvalT;       K=256; N=256; tile=b-256; }
  else if (b < 384){ S=Wdo;  D=WdoT;        K=256; N=256; tile=b-320; }
  else if (b < 512){ S=W1;   D=W1T;         K=256; N=512; tile=b-384; }
  else             { S=W2;   D=W2T;         K=512; N=256; tile=b-512; }
  int ntn = N >> 5;
  int k0 = (tile / ntn) << 5, n0 = (tile % ntn) << 5;
  __shared__ float tl[32][33];
  for (int i = threadIdx.x; i < 1024; i += 256){
    int r = i >> 5, c = i & 31;
    tl[r][c] = S[(size_t)(k0 + r)*N + n0 + c];
  }
  __syncthreads();
  for (int i = threadIdx.x; i < 1024; i += 256){
    int r = i >> 5, c = i & 31;
    D[(size_t)(n0 + r)*K + k0 + c] = __float2bfloat16(tl[c][r]);
  }
}

// ---------------- fused q/k/v projection GEMM: 32 rows x 64 cols, BK=64 ----------------
__global__ void __launch_bounds__(128) qkv_mm_kernel(
    const float* __restrict__ queries, const float* __restrict__ og,
    const bf16* __restrict__ WqkT, const bf16* __restrict__ WvT,
    const float* __restrict__ bq, const float* __restrict__ bk, const float* __restrict__ bv,
    bf16* __restrict__ qh_b, bf16* __restrict__ kh_b, bf16* __restrict__ vt_){
  int t = threadIdx.x, l = t & 63, w = t >> 6, lm = l & 15, lq = l >> 4;
  int row0 = blockIdx.x*32;
  bool isv = blockIdx.y >= 8;
  int col0 = (isv ? (int)blockIdx.y - 8 : (int)blockIdx.y)*64;
  const bf16* B = isv ? WvT : WqkT;
  __shared__ __align__(16) short As[32*72];
  for (int rep = 0; rep < REPEAT; ++rep){
  __syncthreads();
  floatx4 acc[2][2];
  #pragma unroll
  for (int tm = 0; tm < 2; tm++)
    #pragma unroll
    for (int tn = 0; tn < 2; tn++) acc[tm][tn] = (floatx4){0,0,0,0};

  for (int kt = 0; kt < 4; kt++){
    int k0 = kt*64;
    __syncthreads();
    #pragma unroll
    for (int i = 0; i < 4; i++){
      int s = t + i*128;           // 512 float4 slots
      int r = s >> 4, kq = s & 15;
      int rr = row0 + r; if (rr > MT-1) rr = MT-1;
      float4 v = *(const float4*)(queries + (size_t)rr*DM + k0 + kq*4);
      if (!isv){
        float4 u = *(const float4*)(og + (size_t)rr*DM + k0 + kq*4);
        v.x += u.x; v.y += u.y; v.z += u.z; v.w += u.w;
      }
      unsigned int p0 = (unsigned int)f2bu(v.x) | ((unsigned int)f2bu(v.y) << 16);
      unsigned int p1 = (unsigned int)f2bu(v.z) | ((unsigned int)f2bu(v.w) << 16);
      uint2 pk; pk.x = p0; pk.y = p1;
      *(uint2*)&As[r*72 + kq*4] = pk;
    }
    __syncthreads();
    short8 bfr[2][2];
    #pragma unroll
    for (int tn = 0; tn < 2; tn++)
      #pragma unroll
      for (int ks = 0; ks < 2; ks++)
        bfr[tn][ks] = *(const short8*)(const void*)(B + (size_t)(col0 + w*32 + tn*16 + lm)*DM + k0 + ks*32 + lq*8);
    #pragma unroll
    for (int tm = 0; tm < 2; tm++)
      #pragma unroll
      for (int ks = 0; ks < 2; ks++){
        short8 af = *(short8*)&As[(tm*16 + lm)*72 + ks*32 + lq*8];
        #pragma unroll
        for (int tn = 0; tn < 2; tn++)
          acc[tm][tn] = __builtin_amdgcn_mfma_f32_16x16x32_bf16(af, bfr[tn][ks], acc[tm][tn], 0, 0, 0);
      }
  }
  #pragma unroll
  for (int tm = 0; tm < 2; tm++){
    int grow = row0 + tm*16 + lq*4;
    #pragma unroll
    for (int tn = 0; tn < 2; tn++){
      int col = col0 + w*32 + tn*16 + lm;
      #pragma unroll
      for (int r = 0; r < 4; r++){
        int row = grow + r;
        if (row < MT){
          float v = acc[tm][tn][r];
          if (!isv){
            float bb = (col < 256) ? bq[col] : bk[col - 256];
            bf16 o = __float2bfloat16(v + bb);
            if (col < 256) qh_b[(size_t)row*DM + col] = o;
            else           kh_b[(size_t)row*DM + col - 256] = o;
          } else {
            int n = row/QN, q = row - n*QN;
            int h = col >> 5, d = col & 31;
            vt_[((size_t)((n*HH + h)*HD + d))*960 + q] = __float2bfloat16(v + bv[col]);
          }
        }
      }
    }
  }
  } // rep
}

// ---------------- mm2: 32 rows x 64 cols per block, BK=64 (ffn1 only now) ----------------
template<int AM, int KD, int EPI>
__global__ void __launch_bounds__(128) mm2_kernel(
    const void* __restrict__ Aptr,
    const bf16* __restrict__ B, const float* __restrict__ bias,
    const float* __restrict__ res, const float* __restrict__ mask,
    void* __restrict__ out, void* __restrict__ out2nd){
  int t = threadIdx.x, l = t & 63, w = t >> 6, lm = l & 15, lq = l >> 4;
  int row0 = blockIdx.x*32;
  int col0 = blockIdx.y*64;
  __shared__ __align__(16) short As[32*72];
  for (int rep = 0; rep < REPEAT; ++rep){
  __syncthreads();
  floatx4 acc[2][2];
  #pragma unroll
  for (int tm = 0; tm < 2; tm++)
    #pragma unroll
    for (int tn = 0; tn < 2; tn++) acc[tm][tn] = (floatx4){0,0,0,0};

  for (int kt = 0; kt < KD/64; kt++){
    int k0 = kt*64;
    __syncthreads();
    if (AM == 2){
      #pragma unroll
      for (int i = 0; i < 2; i++){
        int s = t + i*128;           // 256 short8 slots
        int r = s >> 3, c = s & 7;
        int rr = row0 + r; if (rr > MT-1) rr = MT-1;
        *(short8*)&As[r*72 + c*8] =
          *(const short8*)(const void*)((const bf16*)Aptr + (size_t)rr*KD + k0 + c*8);
      }
    } else {
      #pragma unroll
      for (int i = 0; i < 4; i++){
        int s = t + i*128;
        int r = s >> 4, kq = s & 15;
        int rr = row0 + r; if (rr > MT-1) rr = MT-1;
        float4 v = *(const float4*)((const float*)Aptr + (size_t)rr*KD + k0 + kq*4);
        unsigned int p0 = (unsigned int)f2bu(v.x) | ((unsigned int)f2bu(v.y) << 16);
        unsigned int p1 = (unsigned int)f2bu(v.z) | ((unsigned int)f2bu(v.w) << 16);
        uint2 pk; pk.x = p0; pk.y = p1;
        *(uint2*)&As[r*72 + kq*4] = pk;
      }
    }
    __syncthreads();
    short8 bfr[2][2];
    #pragma unroll
    for (int tn = 0; tn < 2; tn++)
      #pragma unroll
      for (int ks = 0; ks < 2; ks++)
        bfr[tn][ks] = *(const short8*)(const void*)(B + (size_t)(col0 + w*32 + tn*16 + lm)*KD + k0 + ks*32 + lq*8);
    #pragma unroll
    for (int tm = 0; tm < 2; tm++)
      #pragma unroll
      for (int ks = 0; ks < 2; ks++){
        short8 af = *(short8*)&As[(tm*16 + lm)*72 + ks*32 + lq*8];
        #pragma unroll
        for (int tn = 0; tn < 2; tn++)
          acc[tm][tn] = __builtin_amdgcn_mfma_f32_16x16x32_bf16(af, bfr[tn][ks], acc[tm][tn], 0, 0, 0);
      }
  }
  #pragma unroll
  for (int tm = 0; tm < 2; tm++){
    int grow = row0 + tm*16 + lq*4;
    #pragma unroll
    for (int tn = 0; tn < 2; tn++){
      int col = col0 + w*32 + tn*16 + lm;
      #pragma unroll
      for (int r = 0; r < 4; r++){
        int row = grow + r;
        if (row < MT){
          float v = acc[tm][tn][r];
          if (EPI == 4){
            ((bf16*)out)[(size_t)row*FFD + col] = __float2bfloat16(fmaxf(v + bias[col], 0.f));
          }
        }
      }
    }
  }
  } // rep
}

// ---------------- mmln: GEMM (32 rows x FULL 256-col row, 4 waves x 64 cols) + fused row-LN -
template<int AM, int KD, int V>
__global__ void __launch_bounds__(256) mmln_kernel(
    const void* __restrict__ Aptr, const bf16* __restrict__ B,
    const float* __restrict__ bias, const float* __restrict__ resf,
    const bf16* __restrict__ resb, const float* __restrict__ mask,
    const float* __restrict__ og, const float* __restrict__ g,
    const float* __restrict__ bvec, float* __restrict__ out1,
    void* __restrict__ out2){
  int t = threadIdx.x, l = t & 63, w = t >> 6, lm = l & 15, lq = l >> 4;
  int row0 = blockIdx.x*32;
  __shared__ __align__(16) short As[32*72];
  __shared__ float ob[32][264];
  for (int rep = 0; rep < REPEAT; ++rep){
  __syncthreads();
  floatx4 acc[2][4];
  #pragma unroll
  for (int tm = 0; tm < 2; tm++)
    #pragma unroll
    for (int tn = 0; tn < 4; tn++) acc[tm][tn] = (floatx4){0,0,0,0};

  for (int kt = 0; kt < KD/64; kt++){
    int k0 = kt*64;
    __syncthreads();
    if (AM == 2){
      int r = t >> 3, c = t & 7;
      int rr = row0 + r; if (rr > MT-1) rr = MT-1;
      *(short8*)&As[r*72 + c*8] =
        *(const short8*)(const void*)((const bf16*)Aptr + (size_t)rr*KD + k0 + c*8);
    } else {
      #pragma unroll
      for (int i = 0; i < 2; i++){
        int s = t + i*256;
        int r = s >> 4, kq = s & 15;
        int rr = row0 + r; if (rr > MT-1) rr = MT-1;
        float4 v = *(const float4*)((const float*)Aptr + (size_t)rr*KD + k0 + kq*4);
        unsigned int p0 = (unsigned int)f2bu(v.x) | ((unsigned int)f2bu(v.y) << 16);
        unsigned int p1 = (unsigned int)f2bu(v.z) | ((unsigned int)f2bu(v.w) << 16);
        uint2 pk; pk.x = p0; pk.y = p1;
        *(uint2*)&As[r*72 + kq*4] = pk;
      }
    }
    __syncthreads();
    #pragma unroll
    for (int ks = 0; ks < 2; ks++){
      short8 af0 = *(short8*)&As[(0*16 + lm)*72 + ks*32 + lq*8];
      short8 af1 = *(short8*)&As[(1*16 + lm)*72 + ks*32 + lq*8];
      #pragma unroll
      for (int tn = 0; tn < 4; tn++){
        short8 bfr = *(const short8*)(const void*)(B + (size_t)(w*64 + tn*16 + lm)*KD + k0 + ks*32 + lq*8);
        acc[0][tn] = __builtin_amdgcn_mfma_f32_16x16x32_bf16(af0, bfr, acc[0][tn], 0, 0, 0);
        acc[1][tn] = __builtin_amdgcn_mfma_f32_16x16x32_bf16(af1, bfr, acc[1][tn], 0, 0, 0);
      }
    }
  }
  #pragma unroll
  for (int tm = 0; tm < 2; tm++){
    #pragma unroll
    for (int tn = 0; tn < 4; tn++){
      int col = w*64 + tn*16 + lm;
      #pragma unroll
      for (int r = 0; r < 4; r++){
        int row = tm*16 + lq*4 + r;
        int gr = row0 + row; if (gr > MT-1) gr = MT-1;
        float v = acc[tm][tn][r];
        float pre;
        if (V == 0)      pre = v + bias[col] + resf[(size_t)gr*DM + col];
        else if (V == 1) pre = (v + bias[col])*mask[gr] + resf[(size_t)gr*DM + col];
        else             pre = v + bias[col] + bf2f(resb[(size_t)gr*DM + col]);
        ob[row][col] = pre;
      }
    }
  }
  __syncthreads();
  floatx4 gv = *(const floatx4*)(g + l*4);
  floatx4 bb = *(const floatx4*)(bvec + l*4);
  #pragma unroll
  for (int rr = 0; rr < 8; rr++){
    int row = w*8 + rr;
    int grow = row0 + row;
    floatx4 x = *(floatx4*)&ob[row][l*4];
    float s = x.x + x.y + x.z + x.w;
    #pragma unroll
    for (int off = 1; off < 64; off <<= 1) s += __shfl_xor(s, off);
    float mean = s*(1.f/DM);
    floatx4 c; c.x=x.x-mean; c.y=x.y-mean; c.z=x.z-mean; c.w=x.w-mean;
    float ss = c.x*c.x + c.y*c.y + c.z*c.z + c.w*c.w;
    #pragma unroll
    for (int off = 1; off < 64; off <<= 1) ss += __shfl_xor(ss, off);
    float rstd = rsqrtf(ss*(1.f/DM) + 1e-5f);
    floatx4 o;
    o.x = c.x*rstd*gv.x + bb.x; o.y = c.y*rstd*gv.y + bb.y;
    o.z = c.z*rstd*gv.z + bb.z; o.w = c.w*rstd*gv.w + bb.w;
    if (grow < MT){
      if (V == 0){
        *(floatx4*)(out1 + (size_t)grow*DM + l*4) = o;
        floatx4 ogv = *(const floatx4*)(og + (size_t)grow*DM + l*4);
        floatx4 a2; a2.x=o.x+ogv.x; a2.y=o.y+ogv.y; a2.z=o.z+ogv.z; a2.w=o.w+ogv.w;
        *(floatx4*)((float*)out2 + (size_t)grow*DM + l*4) = a2;
      } else if (V == 1){
        bf16* d = (bf16*)out2 + (size_t)grow*DM + l*4;
        d[0]=__float2bfloat16(o.x); d[1]=__float2bfloat16(o.y);
        d[2]=__float2bfloat16(o.z); d[3]=__float2bfloat16(o.w);
      } else {
        *(floatx4*)((float*)out2 + (size_t)grow*DM + l*4) = o;
      }
    }
  }
  } // rep
}

// ---------------- K2: flash MHA, bf16 MFMA; block = 32 q-rows (2 waves x 16) ----------------
__global__ void __launch_bounds__(128) mha_flash(const bf16* __restrict__ qh_b,
                                                 const bf16* __restrict__ kh_b,
                                                 const bf16* __restrict__ vt,
                                                 const float* __restrict__ mask,
                                                 bf16* __restrict__ attn_b){
  int qt = blockIdx.x, h = blockIdx.y, n = blockIdx.z;
  int t = threadIdx.x, l = t & 63, w = t >> 6;
  int q0 = qt*32;
  __shared__ short Qs[32*40];
  __shared__ short Ks[64*40];
  __shared__ short Vts[32*72];
  __shared__ short Ps[2][16*72];
  int lm = l & 15, lq = l >> 4;
  const float scale = 0.17677669529663687f;
  for (int rep = 0; rep < REPEAT; ++rep){
  __syncthreads();
  {
    int r = t >> 2, q = t & 3;
    int qr = q0 + r; if (qr > QN-1) qr = QN-1;
    *(short8*)&Qs[r*40 + q*8] = *(const short8*)(const void*)(qh_b + (size_t)(n*QN + qr)*DM + h*32 + q*8);
  }
  floatx4 O[2]; O[0] = (floatx4){0,0,0,0}; O[1] = (floatx4){0,0,0,0};
  float mo[4] = {-1e30f,-1e30f,-1e30f,-1e30f};
  float li[4] = {0.f,0.f,0.f,0.f};
  for (int kt = 0; kt < 15; kt++){
    int kk0 = kt*64;
    __syncthreads();
    #pragma unroll
    for (int i = 0; i < 2; i++){
      int idx = t + i*128;
      int r = idx >> 2, q = idx & 3;
      int kr = kk0 + r; if (kr > QN-1) kr = QN-1;
      *(short8*)&Ks[r*40 + q*8] = *(const short8*)(const void*)(kh_b + (size_t)(n*QN + kr)*DM + h*32 + q*8);
    }
    #pragma unroll
    for (int i = 0; i < 2; i++){
      int idx = t + i*128;
      int d = idx >> 3, q = idx & 7;
      *(short8*)&Vts[d*72 + q*8] = *(const short8*)(const void*)(vt + ((size_t)((n*HH + h)*HD) + d)*960 + kk0 + q*8);
    }
    __syncthreads();
    short8 af = *(short8*)&Qs[(w*16 + lm)*40 + lq*8];
    floatx4 S[4];
    #pragma unroll
    for (int tn = 0; tn < 4; tn++){
      short8 bfr = *(short8*)&Ks[(tn*16 + lm)*40 + lq*8];
      S[tn] = __builtin_amdgcn_mfma_f32_16x16x32_bf16(af, bfr, (floatx4){0,0,0,0}, 0, 0, 0);
    }
    #pragma unroll
    for (int tn = 0; tn < 4; tn++){
      int kk = kk0 + tn*16 + lm;
      int kc = kk > QN-1 ? QN-1 : kk;
      bool keep = (kk < QN) && (mask[(size_t)n*QN + kc] > 0.f);
      #pragma unroll
      for (int r = 0; r < 4; r++)
        S[tn][r] = keep ? S[tn][r]*scale : -1e9f;
    }
    float mnew[4], alpha[4];
    #pragma unroll
    for (int r = 0; r < 4; r++){
      float m = fmaxf(fmaxf(S[0][r], S[1][r]), fmaxf(S[2][r], S[3][r]));
      #pragma unroll
      for (int off = 1; off < 16; off <<= 1) m = fmaxf(m, __shfl_xor(m, off));
      mnew[r] = fmaxf(mo[r], m);
      alpha[r] = __expf(mo[r] - mnew[r]);
      mo[r] = mnew[r];
    }
    #pragma unroll
    for (int tn = 0; tn < 4; tn++)
      #pragma unroll
      for (int r = 0; r < 4; r++)
        S[tn][r] = __expf(S[tn][r] - mnew[r]);
    #pragma unroll
    for (int r = 0; r < 4; r++){
      float s = S[0][r] + S[1][r] + S[2][r] + S[3][r];
      #pragma unroll
      for (int off = 1; off < 16; off <<= 1) s += __shfl_xor(s, off);
      li[r] = li[r]*alpha[r] + s;
      O[0][r] *= alpha[r];
      O[1][r] *= alpha[r];
    }
    #pragma unroll
    for (int tn = 0; tn < 4; tn++)
      #pragma unroll
      for (int r = 0; r < 4; r++)
        Ps[w][(lq*4 + r)*72 + tn*16 + lm] = (short)f2bu(S[tn][r]);
    __syncthreads();
    #pragma unroll
    for (int s = 0; s < 2; s++){
      short8 pf = *(short8*)&Ps[w][lm*72 + s*32 + lq*8];
      #pragma unroll
      for (int tn2 = 0; tn2 < 2; tn2++){
        short8 vf = *(short8*)&Vts[(tn2*16 + lm)*72 + s*32 + lq*8];
        O[tn2] = __builtin_amdgcn_mfma_f32_16x16x32_bf16(pf, vf, O[tn2], 0, 0, 0);
      }
    }
  }
  #pragma unroll
  for (int r = 0; r < 4; r++){
    int row = q0 + w*16 + lq*4 + r;
    if (row < QN){
      float inv = 1.f/li[r];
      attn_b[(size_t)(n*QN + row)*DM + h*32 + lm]      = __float2bfloat16(O[0][r]*inv);
      attn_b[(size_t)(n*QN + row)*DM + h*32 + 16 + lm] = __float2bfloat16(O[1][r]*inv);
    }
  }
  } // rep
}

// ---------------- off/attn GEMV + softmax + sample coords (reads aug) ----------------
__global__ void __launch_bounds__(128) off_attn_kernel(
    const float* __restrict__ aug, const float* __restrict__ ref,
    const bf16* __restrict__ Woffb, const float* __restrict__ boff,
    const bf16* __restrict__ Wattnb, const float* __restrict__ battn,
    float* __restrict__ locb, float* __restrict__ awb){
  int row = blockIdx.x, t = threadIdx.x;
  __shared__ float a[DM]; __shared__ float offL[64]; __shared__ float awL[32];
  for (int rep = 0; rep < REPEAT; ++rep){
  __syncthreads();
  a[t]       = aug[(size_t)row*DM + t];
  a[t + 128] = aug[(size_t)row*DM + t + 128];
  __syncthreads();
  if (t < 64){
    float acc = boff[t];
    for (int k = 0; k < DM; k++) acc += a[k]*bf2f(Woffb[k*64 + t]);
    offL[t] = acc;
  } else if (t < 96){
    int j = t - 64;
    float acc = battn[j];
    for (int k = 0; k < DM; k++) acc += a[k]*bf2f(Wattnb[k*32 + j]);
    awL[j] = acc;
  }
  __syncthreads();
  if (t < 64){
    int c = t & 1;
    float refv = ref[row*2 + c];
    locb[row*64 + t] = refv*200.0f + offL[t] - 0.5f;
  }
  if (t < 8){
    float m = -1e30f;
    #pragma unroll
    for (int p = 0; p < 4; p++) m = fmaxf(m, awL[t*4 + p]);
    float e[4]; float sm = 0.f;
    #pragma unroll
    for (int p = 0; p < 4; p++){ e[p] = __expf(awL[t*4 + p] - m); sm += e[p]; }
    #pragma unroll
    for (int p = 0; p < 4; p++) awb[row*32 + t*4 + p] = e[p]/sm;
  }
  } // rep
}

// ---------------- K6'': dedup'd bilinear gather + Wval projection, 4 rows/block --------
__global__ void __launch_bounds__(256) deform_proj_kernel(
    const float* __restrict__ bev, const float* __restrict__ locb,
    const float* __restrict__ awb, const bf16* __restrict__ WvalT,
    const float* __restrict__ bval, float* __restrict__ sampled){
  int t = threadIdx.x, l = t & 63, wvi = t >> 6;
  int row0 = blockIdx.x*RPB;
  int rowW = row0 + wvi;
  __shared__ float locS[RPB][64];
  __shared__ float awS[RPB][32];
  __shared__ int   pcS[RPB][128];
  __shared__ float wS[RPB][128];
  __shared__ float wtabS[RPB][8][16];
  __shared__ int   cellListS[RPB][16];
  __shared__ int   ndS[RPB];
  __shared__ float wsumS[RPB][8];
  __shared__ float aggS[RPB][8][DM];
  for (int rep = 0; rep < REPEAT; ++rep){
  __syncthreads();
  locS[wvi][l] = locb[(size_t)rowW*64 + l];
  if (l < 32) awS[wvi][l] = awb[(size_t)rowW*32 + l];

  int pk0[2]; float w0[2];
  #pragma unroll
  for (int i = 0; i < 2; i++){
    int e = l + i*64;
    int h = e >> 4, j = e & 15, p = j >> 2, c = j & 3, dx = c & 1, dy = c >> 1;
    float x = locS[wvi][h*8 + p*2], y = locS[wvi][h*8 + p*2 + 1];
    float aw = awS[wvi][h*4 + p];
    float x0f = floorf(x), y0f = floorf(y);
    float fx = x - x0f, fy = y - y0f;
    int xc = (int)x0f + dx, yc = (int)y0f + dy;
    float wg = (dx ? fx : 1.f - fx) * (dy ? fy : 1.f - fy);
    bool ok = (xc >= 0) && (xc < WBg) && (yc >= 0) && (yc < HBg);
    pk0[i] = ok ? ((yc << 16) | xc) : -1;
    w0[i]  = ok ? aw*wg : 0.f;
    pcS[wvi][e] = pk0[i];
    wS[wvi][e]  = w0[i];
  }

  int mnx = 0x7fff, mny = 0x7fff, mxx = -1, mxy = -1;
  #pragma unroll
  for (int i = 0; i < 2; i++){
    if (pk0[i] >= 0){
      int x = pk0[i] & 0xffff, y = pk0[i] >> 16;
      mnx = min(mnx, x); mxx = max(mxx, x);
      mny = min(mny, y); mxy = max(mxy, y);
    }
  }
  #pragma unroll
  for (int off = 32; off; off >>= 1){
    mnx = min(mnx, __shfl_xor(mnx, off));
    mxx = max(mxx, __shfl_xor(mxx, off));
    mny = min(mny, __shfl_xor(mny, off));
    mxy = max(mxy, __shfl_xor(mxy, off));
  }
  int nd, bw = 1;
  if (mxx < 0) nd = 0;
  else {
    bw = mxx - mnx + 1; int bh = mxy - mny + 1;
    nd = (bw <= 16 && bh <= 16 && bw*bh <= 16) ? bw*bh : -1;
  }
  if (l == 0) ndS[wvi] = nd;

  if (nd > 0){
    #pragma unroll
    for (int i = 0; i < 2; i++){
      int s = l + i*64;
      int h = s >> 4, ci = s & 15;
      if (ci < nd){
        int cy = mny + ci / bw, cx = mnx + ci % bw;
        int pk = (cy << 16) | cx;
        float w = 0.f;
        #pragma unroll
        for (int j = 0; j < 16; j++)
          if (pcS[wvi][h*16 + j] == pk) w += wS[wvi][h*16 + j];
        wtabS[wvi][h][ci] = w;
        if (h == 0) cellListS[wvi][ci] = cy*WBg + cx;
      }
    }
  }
  if (l < 8){
    float s = 0.f;
    #pragma unroll
    for (int j = 0; j < 16; j++) s += wS[wvi][l*16 + j];
    wsumS[wvi][l] = s;
  }
  __syncthreads();

  float agg[RPB][8];
  #pragma unroll
  for (int r = 0; r < RPB; r++)
    #pragma unroll
    for (int h = 0; h < 8; h++) agg[r][h] = 0.f;
  #pragma unroll
  for (int r = 0; r < RPB; r++){
    int n = (row0 + r)/QN;
    const float* bevn = bev + (size_t)n*NV*DM + t;
    int nd_r = ndS[r];
    if (nd_r >= 0){
      for (int ci = 0; ci < nd_r; ci++){
        float v = bevn[(size_t)cellListS[r][ci]*DM];
        #pragma unroll
        for (int h = 0; h < 8; h++) agg[r][h] += wtabS[r][h][ci]*v;
      }
    } else {
      #pragma unroll
      for (int h = 0; h < 8; h++){
        for (int j = 0; j < 16; j++){
          int pk = pcS[r][h*16 + j];
          if (pk >= 0){
            int cell = (pk >> 16)*WBg + (pk & 0xffff);
            agg[r][h] += wS[r][h*16 + j]*bevn[(size_t)cell*DM];
          }
        }
      }
    }
    #pragma unroll
    for (int h = 0; h < 8; h++) aggS[r][h][t] = agg[r][h];
  }
  __syncthreads();

  int h2 = t >> 5;
  const bf16* wrow = WvalT + (size_t)t*DM;
  float outv[RPB];
  float bvt = bval[t];
  #pragma unroll
  for (int r = 0; r < RPB; r++) outv[r] = wsumS[r][h2]*bvt;
  #pragma unroll 2
  for (int kb = 0; kb < 32; kb++){
    short8 wv8 = *(const short8*)(const void*)(wrow + kb*8);
    const bf16* wp = (const bf16*)&wv8;
    float wf[8];
    #pragma unroll
    for (int j = 0; j < 8; j++) wf[j] = bf2f(wp[j]);
    #pragma unroll
    for (int r = 0; r < RPB; r++){
      floatx4 a0 = *(floatx4*)&aggS[r][h2][kb*8];
      floatx4 a1 = *(floatx4*)&aggS[r][h2][kb*8 + 4];
      outv[r] += a0.x*wf[0] + a0.y*wf[1] + a0.z*wf[2] + a0.w*wf[3]
               + a1.x*wf[4] + a1.y*wf[5] + a1.z*wf[6] + a1.w*wf[7];
    }
  }
  #pragma unroll
  for (int r = 0; r < RPB; r++)
    sampled[(size_t)(row0 + r)*DM + t] = outv[r];
  } // rep
}

extern "C" void kernel_launch(void* const* d_in, const int* in_sizes, int n_in,
                              void* d_out, int out_size, void* d_ws, size_t ws_size,
                              hipStream_t stream) {
  const float* queries = (const float*)d_in[0];
  const float* bev     = (const float*)d_in[1];
  const float* ref     = (const float*)d_in[2];
  const float* og      = (const float*)d_in[3];
  const float* mask    = (const float*)d_in[4];
  const float* Wq = (const float*)d_in[5];  const float* bq = (const float*)d_in[6];
  const float* Wk = (const float*)d_in[7];  const float* bk = (const float*)d_in[8];
  const float* Wv = (const float*)d_in[9];  const float* bv = (const float*)d_in[10];
  const float* Wo = (const float*)d_in[11]; const float* bo = (const float*)d_in[12];
  const float* ln1g = (const float*)d_in[13]; const float* ln1b = (const float*)d_in[14];
  const float* Wval = (const float*)d_in[15]; const float* bval = (const float*)d_in[16];
  const float* Woff = (const float*)d_in[17]; const float* boff = (const float*)d_in[18];
  const float* Wattn = (const float*)d_in[19]; const float* battn = (const float*)d_in[20];
  const float* Wdo = (const float*)d_in[21]; const float* bdo = (const float*)d_in[22];
  const float* ln2g = (const float*)d_in[23]; const float* ln2b = (const float*)d_in[24];
  const float* W1 = (const float*)d_in[25]; const float* b1 = (const float*)d_in[26];
  const float* W2 = (const float*)d_in[27]; const float* b2 = (const float*)d_in[28];
  const float* ln3g = (const float*)d_in[29]; const float* ln3b = (const float*)d_in[30];

  char* base = (char*)d_ws;
  bf16*  WqkT   = (bf16*)base;  base += 262144;   // [512][256]
  bf16*  WvT    = (bf16*)base;  base += 131072;
  bf16*  WoT    = (bf16*)base;  base += 131072;
  bf16*  WvalT  = (bf16*)base;  base += 131072;
  bf16*  WdoT   = (bf16*)base;  base += 131072;
  bf16*  W1T    = (bf16*)base;  base += 262144;   // [512][256]
  bf16*  W2T    = (bf16*)base;  base += 262144;   // [256][512]
  bf16*  Woffb  = (bf16*)base;  base += 32768;
  bf16*  Wattnb = (bf16*)base;  base += 16384;
  bf16*  qh_b   = (bf16*)base;  base += 1843200;
  bf16*  kh_b   = (bf16*)base;  base += 1843200;
  bf16*  vt     = (bf16*)base;  base += 1966080;  // [1024][960]
  bf16*  attn_b = (bf16*)base;  base += 1843200;
  float* out2   = (float*)base; base += 3686400;
  float* aug    = (float*)base; base += 3686400;
  float* sampled= (float*)base; base += 3686400;
  bf16*  out4_b = (bf16*)base;  base += 1843200;
  bf16*  hid    = (bf16*)base;  base += 3686400;  // [3600][512] bf16
  float* locb   = (float*)base; base += 921600;
  float* awb    = (float*)base; base += 460800;

  cvtAll<<<736, 256, 0, stream>>>(Wq, Wk, Wv, Wo, Wval, Wdo, W1, W2, Woff, Wattn,
                                  WqkT, WvT, WoT, WvalT, WdoT, W1T, W2T, Woffb, Wattnb);
  qkv_mm_kernel<<<dim3(113, 12), 128, 0, stream>>>(queries, og, WqkT, WvT, bq, bk, bv,
                                                   qh_b, kh_b, vt);
  mha_flash<<<dim3(29, HH, NB), 128, 0, stream>>>(qh_b, kh_b, vt, mask, attn_b);
  mmln_kernel<2,256,0><<<113, 256, 0, stream>>>(attn_b, WoT, bo, queries, nullptr, nullptr,
                                                og, ln1g, ln1b, out2, aug);
  off_attn_kernel<<<MT, 128, 0, stream>>>(aug, ref, Woffb, boff, Wattnb, battn, locb, awb);
  deform_proj_kernel<<<MT/RPB, 256, 0, stream>>>(bev, locb, awb, WvalT, bval, sampled);
  mmln_kernel<0,256,1><<<113, 256, 0, stream>>>(sampled, WdoT, bdo, out2, nullptr, mask,
                                                nullptr, ln2g, ln2b, nullptr, out4_b);
  mm2_kernel<2,256,4><<<dim3(113,8), 128, 0, stream>>>(out4_b, W1T, b1, nullptr, nullptr,
                                                       hid, nullptr);
  mmln_kernel<2,512,2><<<113, 256, 0, stream>>>(hid, W2T, b2, nullptr, out4_b, nullptr,
                                                nullptr, ln3g, ln3b, nullptr, (float*)d_out);
}

// Round 15
// 394.227 us; speedup vs baseline: 3.2286x; 3.2286x over previous
//
#include <hip/hip_runtime.h>
#include <hip/hip_bf16.h>
#include <cstddef>

#define NB  4
#define QN  900
#define DM  256
#define HH  8
#define HD  32
#define PP  4
#define HBg 200
#define WBg 200
#define FFD 512
#define NV  (HBg*WBg)   // 40000 bev cells
#define RPB 4           // deform: queries (rows) per block
#define MT  3600        // total rows

typedef __hip_bfloat16 bf16;
typedef __attribute__((ext_vector_type(8))) short short8;
typedef __attribute__((ext_vector_type(4))) float floatx4;

__device__ __forceinline__ float bf2f(bf16 x){ return __bfloat162float(x); }
__device__ __forceinline__ unsigned short f2bu(float f){
  bf16 h = __float2bfloat16(f);
  return *(unsigned short*)&h;
}

// ---------------- K0: fused transpose+convert of all GEMM weights + Woff/Wattn ----------------
__global__ void __launch_bounds__(256) cvtAll(
    const float* __restrict__ Wq, const float* __restrict__ Wk,
    const float* __restrict__ Wv, const float* __restrict__ Wo,
    const float* __restrict__ Wval, const float* __restrict__ Wdo,
    const float* __restrict__ W1, const float* __restrict__ W2,
    const float* __restrict__ Woff, const float* __restrict__ Wattn,
    bf16* __restrict__ WqkT, bf16* __restrict__ WvT, bf16* __restrict__ WoT,
    bf16* __restrict__ WvalT, bf16* __restrict__ WdoT,
    bf16* __restrict__ W1T, bf16* __restrict__ W2T,
    bf16* __restrict__ Woffb, bf16* __restrict__ Wattnb){
  int b = blockIdx.x;
  if (b >= 640){
    int i = (b - 640)*256 + threadIdx.x;
    if (i < 16384) Woffb[i] = __float2bfloat16(Woff[i]);
    else if (i < 24576) Wattnb[i - 16384] = __float2bfloat16(Wattn[i - 16384]);
    return;
  }
  const float* S; bf16* D; int K, N, tile;
  if      (b <  64){ S=Wq;   D=WqkT;        K=256; N=256; tile=b; }
  else if (b < 128){ S=Wk;   D=WqkT+65536;  K=256; N=256; tile=b-64; }
  else if (b < 192){ S=Wv;   D=WvT;         K=256; N=256; tile=b-128; }
  else if (b < 256){ S=Wo;   D=WoT;         K=256; N=256; tile=b-192; }
  else if (b < 320){ S=Wval; D=WvalT;       K=256; N=256; tile=b-256; }
  else if (b < 384){ S=Wdo;  D=WdoT;        K=256; N=256; tile=b-320; }
  else if (b < 512){ S=W1;   D=W1T;         K=256; N=512; tile=b-384; }
  else             { S=W2;   D=W2T;         K=512; N=256; tile=b-512; }
  int ntn = N >> 5;
  int k0 = (tile / ntn) << 5, n0 = (tile % ntn) << 5;
  __shared__ float tl[32][33];
  for (int i = threadIdx.x; i < 1024; i += 256){
    int r = i >> 5, c = i & 31;
    tl[r][c] = S[(size_t)(k0 + r)*N + n0 + c];
  }
  __syncthreads();
  for (int i = threadIdx.x; i < 1024; i += 256){
    int r = i >> 5, c = i & 31;
    D[(size_t)(n0 + r)*K + k0 + c] = __float2bfloat16(tl[c][r]);
  }
}

// ---------------- fused q/k/v projection GEMM: 32 rows x 64 cols, BK=64 ----------------
__global__ void __launch_bounds__(128) qkv_mm_kernel(
    const float* __restrict__ queries, const float* __restrict__ og,
    const bf16* __restrict__ WqkT, const bf16* __restrict__ WvT,
    const float* __restrict__ bq, const float* __restrict__ bk, const float* __restrict__ bv,
    bf16* __restrict__ qh_b, bf16* __restrict__ kh_b, bf16* __restrict__ vt_){
  int t = threadIdx.x, l = t & 63, w = t >> 6, lm = l & 15, lq = l >> 4;
  int row0 = blockIdx.x*32;
  bool isv = blockIdx.y >= 8;
  int col0 = (isv ? (int)blockIdx.y - 8 : (int)blockIdx.y)*64;
  const bf16* B = isv ? WvT : WqkT;
  __shared__ __align__(16) short As[32*72];
  floatx4 acc[2][2];
  #pragma unroll
  for (int tm = 0; tm < 2; tm++)
    #pragma unroll
    for (int tn = 0; tn < 2; tn++) acc[tm][tn] = (floatx4){0,0,0,0};

  for (int kt = 0; kt < 4; kt++){
    int k0 = kt*64;
    __syncthreads();
    #pragma unroll
    for (int i = 0; i < 4; i++){
      int s = t + i*128;           // 512 float4 slots
      int r = s >> 4, kq = s & 15;
      int rr = row0 + r; if (rr > MT-1) rr = MT-1;
      float4 v = *(const float4*)(queries + (size_t)rr*DM + k0 + kq*4);
      if (!isv){
        float4 u = *(const float4*)(og + (size_t)rr*DM + k0 + kq*4);
        v.x += u.x; v.y += u.y; v.z += u.z; v.w += u.w;
      }
      unsigned int p0 = (unsigned int)f2bu(v.x) | ((unsigned int)f2bu(v.y) << 16);
      unsigned int p1 = (unsigned int)f2bu(v.z) | ((unsigned int)f2bu(v.w) << 16);
      uint2 pk; pk.x = p0; pk.y = p1;
      *(uint2*)&As[r*72 + kq*4] = pk;
    }
    __syncthreads();
    short8 bfr[2][2];
    #pragma unroll
    for (int tn = 0; tn < 2; tn++)
      #pragma unroll
      for (int ks = 0; ks < 2; ks++)
        bfr[tn][ks] = *(const short8*)(const void*)(B + (size_t)(col0 + w*32 + tn*16 + lm)*DM + k0 + ks*32 + lq*8);
    #pragma unroll
    for (int tm = 0; tm < 2; tm++)
      #pragma unroll
      for (int ks = 0; ks < 2; ks++){
        short8 af = *(short8*)&As[(tm*16 + lm)*72 + ks*32 + lq*8];
        #pragma unroll
        for (int tn = 0; tn < 2; tn++)
          acc[tm][tn] = __builtin_amdgcn_mfma_f32_16x16x32_bf16(af, bfr[tn][ks], acc[tm][tn], 0, 0, 0);
      }
  }
  #pragma unroll
  for (int tm = 0; tm < 2; tm++){
    int grow = row0 + tm*16 + lq*4;
    #pragma unroll
    for (int tn = 0; tn < 2; tn++){
      int col = col0 + w*32 + tn*16 + lm;
      #pragma unroll
      for (int r = 0; r < 4; r++){
        int row = grow + r;
        if (row < MT){
          float v = acc[tm][tn][r];
          if (!isv){
            float bb = (col < 256) ? bq[col] : bk[col - 256];
            bf16 o = __float2bfloat16(v + bb);
            if (col < 256) qh_b[(size_t)row*DM + col] = o;
            else           kh_b[(size_t)row*DM + col - 256] = o;
          } else {
            int n = row/QN, q = row - n*QN;
            int h = col >> 5, d = col & 31;
            vt_[((size_t)((n*HH + h)*HD + d))*960 + q] = __float2bfloat16(v + bv[col]);
          }
        }
      }
    }
  }
}

// ---------------- unified MFMA GEMM v2: 32 rows x 64 cols per block, BK=64 ----------------
// AM: 0 = fp32 A, 2 = bf16 A.
// EPI: 2 +bias+res fp32 (Wo), 3 (+bias)*mask+res fp32 (Wdo),
//      4 relu bf16 stride FFD (W1), 5 +bias+bf16res fp32 (W2)
template<int AM, int KD, int EPI>
__global__ void __launch_bounds__(128) mm2_kernel(
    const void* __restrict__ Aptr,
    const bf16* __restrict__ B, const float* __restrict__ bias,
    const float* __restrict__ res, const float* __restrict__ mask,
    void* __restrict__ out, void* __restrict__ out2nd){
  int t = threadIdx.x, l = t & 63, w = t >> 6, lm = l & 15, lq = l >> 4;
  int row0 = blockIdx.x*32;
  int col0 = blockIdx.y*64;
  __shared__ __align__(16) short As[32*72];
  floatx4 acc[2][2];
  #pragma unroll
  for (int tm = 0; tm < 2; tm++)
    #pragma unroll
    for (int tn = 0; tn < 2; tn++) acc[tm][tn] = (floatx4){0,0,0,0};

  for (int kt = 0; kt < KD/64; kt++){
    int k0 = kt*64;
    __syncthreads();
    if (AM == 2){
      #pragma unroll
      for (int i = 0; i < 2; i++){
        int s = t + i*128;           // 256 short8 slots
        int r = s >> 3, c = s & 7;
        int rr = row0 + r; if (rr > MT-1) rr = MT-1;
        *(short8*)&As[r*72 + c*8] =
          *(const short8*)(const void*)((const bf16*)Aptr + (size_t)rr*KD + k0 + c*8);
      }
    } else {
      #pragma unroll
      for (int i = 0; i < 4; i++){
        int s = t + i*128;
        int r = s >> 4, kq = s & 15;
        int rr = row0 + r; if (rr > MT-1) rr = MT-1;
        float4 v = *(const float4*)((const float*)Aptr + (size_t)rr*KD + k0 + kq*4);
        unsigned int p0 = (unsigned int)f2bu(v.x) | ((unsigned int)f2bu(v.y) << 16);
        unsigned int p1 = (unsigned int)f2bu(v.z) | ((unsigned int)f2bu(v.w) << 16);
        uint2 pk; pk.x = p0; pk.y = p1;
        *(uint2*)&As[r*72 + kq*4] = pk;
      }
    }
    __syncthreads();
    short8 bfr[2][2];
    #pragma unroll
    for (int tn = 0; tn < 2; tn++)
      #pragma unroll
      for (int ks = 0; ks < 2; ks++)
        bfr[tn][ks] = *(const short8*)(const void*)(B + (size_t)(col0 + w*32 + tn*16 + lm)*KD + k0 + ks*32 + lq*8);
    #pragma unroll
    for (int tm = 0; tm < 2; tm++)
      #pragma unroll
      for (int ks = 0; ks < 2; ks++){
        short8 af = *(short8*)&As[(tm*16 + lm)*72 + ks*32 + lq*8];
        #pragma unroll
        for (int tn = 0; tn < 2; tn++)
          acc[tm][tn] = __builtin_amdgcn_mfma_f32_16x16x32_bf16(af, bfr[tn][ks], acc[tm][tn], 0, 0, 0);
      }
  }
  // C layout: col = lane&15, row = (lane>>4)*4 + reg
  #pragma unroll
  for (int tm = 0; tm < 2; tm++){
    int grow = row0 + tm*16 + lq*4;
    #pragma unroll
    for (int tn = 0; tn < 2; tn++){
      int col = col0 + w*32 + tn*16 + lm;
      #pragma unroll
      for (int r = 0; r < 4; r++){
        int row = grow + r;
        if (row < MT){
          float v = acc[tm][tn][r];
          if (EPI == 2){
            ((float*)out)[(size_t)row*DM + col] = v + bias[col] + res[(size_t)row*DM + col];
          } else if (EPI == 3){
            ((float*)out)[(size_t)row*DM + col] = (v + bias[col])*mask[row] + res[(size_t)row*DM + col];
          } else if (EPI == 4){
            ((bf16*)out)[(size_t)row*FFD + col] = __float2bfloat16(fmaxf(v + bias[col], 0.f));
          } else {
            ((float*)out)[(size_t)row*DM + col] = v + bias[col] + bf2f(((const bf16*)out2nd)[(size_t)row*DM + col]);
          }
        }
      }
    }
  }
}

// ---------------- LN: row per wave, shuffle reduce. MODE 1: ->bf16; 2: ->fp32
template<int MODE>
__global__ void __launch_bounds__(256) ln_kernel(
    const float* __restrict__ lin, const float* __restrict__ g, const float* __restrict__ b,
    void* __restrict__ o2){
  int wv = threadIdx.x >> 6, l = threadIdx.x & 63;
  int row = blockIdx.x*4 + wv;
  floatx4 v = *(const floatx4*)(lin + (size_t)row*DM + l*4);
  float s = v.x + v.y + v.z + v.w;
  #pragma unroll
  for (int off = 1; off < 64; off <<= 1) s += __shfl_xor(s, off);
  float mean = s*(1.f/DM);
  floatx4 c; c.x = v.x-mean; c.y = v.y-mean; c.z = v.z-mean; c.w = v.w-mean;
  float ss = c.x*c.x + c.y*c.y + c.z*c.z + c.w*c.w;
  #pragma unroll
  for (int off = 1; off < 64; off <<= 1) ss += __shfl_xor(ss, off);
  float rstd = rsqrtf(ss*(1.f/DM) + 1e-5f);
  floatx4 gv = *(const floatx4*)(g + l*4);
  floatx4 bv = *(const floatx4*)(b + l*4);
  floatx4 o;
  o.x = c.x*rstd*gv.x + bv.x; o.y = c.y*rstd*gv.y + bv.y;
  o.z = c.z*rstd*gv.z + bv.z; o.w = c.w*rstd*gv.w + bv.w;
  if (MODE == 1){
    bf16* d = (bf16*)o2 + (size_t)row*DM + l*4;
    d[0] = __float2bfloat16(o.x); d[1] = __float2bfloat16(o.y);
    d[2] = __float2bfloat16(o.z); d[3] = __float2bfloat16(o.w);
  } else {
    *(floatx4*)((float*)o2 + (size_t)row*DM + l*4) = o;
  }
}

// ---------------- K2': barrier-free split-K flash MHA, swapped-operand MFMA ----------------
// Block 256 thr (4 waves), 32 q rows. Each wave owns key-groups g = w, w+4, ... (32 keys each),
// runs a private online softmax (swapped mfma(K,Q): lane q = lane&15 -> reductions are 2 shfl),
// P stays in registers (packed-bf16 lane-permute builds the PV B-fragment), zero barriers in
// the k-loop. One LDS flash-merge of the 4 partials at the end.
__global__ void __launch_bounds__(256) mha_flash(const bf16* __restrict__ qh_b,
                                                 const bf16* __restrict__ kh_b,
                                                 const bf16* __restrict__ vt,
                                                 const float* __restrict__ mask,
                                                 bf16* __restrict__ attn_b){
  int qt = blockIdx.x, h = blockIdx.y, n = blockIdx.z;
  int t = threadIdx.x, l = t & 63, w = t >> 6;
  int lm = l & 15, lq = l >> 4;
  int q0 = qt*32;
  const float scale = 0.17677669529663687f;
  __shared__ float mS[4][32];
  __shared__ float lS[4][32];
  __shared__ float OS[4][32][33];

  // Q B-fragments: lane holds Q[q = tm*16+lm][d = lq*8 .. +8]
  short8 qf[2];
  #pragma unroll
  for (int tm = 0; tm < 2; tm++){
    int qr = q0 + tm*16 + lm; if (qr > QN-1) qr = QN-1;
    qf[tm] = *(const short8*)(const void*)(qh_b + (size_t)(n*QN + qr)*DM + h*32 + lq*8);
  }
  floatx4 O[2][2];   // [tm][dt]; O^T layout: col=q=lm, row=d=dt*16+lq*4+r
  #pragma unroll
  for (int tm = 0; tm < 2; tm++)
    #pragma unroll
    for (int dt = 0; dt < 2; dt++) O[tm][dt] = (floatx4){0,0,0,0};
  float mo[2] = {-1e30f, -1e30f}, li[2] = {0.f, 0.f};

  const bf16*  kbase = kh_b + (size_t)n*QN*DM + h*32;
  const bf16*  vbase = vt + (size_t)((n*HH + h)*HD)*960;
  const float* mbase = mask + (size_t)n*QN;
  int lqa = lq & 1, hi = lq >> 1;

  for (int g = w; g < 29; g += 4){
    int k0 = g*32;
    // K A-fragments: lane holds K[key = tt*16+lm][d = lq*8 .. +8]
    short8 kf[2];
    #pragma unroll
    for (int tt = 0; tt < 2; tt++){
      int kr = k0 + tt*16 + lm; if (kr > QN-1) kr = QN-1;
      kf[tt] = *(const short8*)(const void*)(kbase + (size_t)kr*DM + lq*8);
    }
    bool keep[2][4];
    #pragma unroll
    for (int tt = 0; tt < 2; tt++)
      #pragma unroll
      for (int r = 0; r < 4; r++){
        int kk = k0 + tt*16 + lq*4 + r;
        int kc = kk > QN-1 ? QN-1 : kk;
        keep[tt][r] = (kk < QN) && (mbase[kc] > 0.f);
      }
    // V A-fragments (pre-transposed vt; pad cols 900..959 zeroed by memset)
    short8 vf[2];
    #pragma unroll
    for (int dt = 0; dt < 2; dt++)
      vf[dt] = *(const short8*)(const void*)(vbase + (size_t)(dt*16 + lm)*960 + k0 + lq*8);

    float p[2][8];   // [tm][tt*4+r]: lane's P values for q=tm*16+lm, keys k0+tt*16+lq*4+r
    #pragma unroll
    for (int tm = 0; tm < 2; tm++){
      // swapped: out row = key, col = q
      floatx4 s0 = __builtin_amdgcn_mfma_f32_16x16x32_bf16(kf[0], qf[tm], (floatx4){0,0,0,0}, 0, 0, 0);
      floatx4 s1 = __builtin_amdgcn_mfma_f32_16x16x32_bf16(kf[1], qf[tm], (floatx4){0,0,0,0}, 0, 0, 0);
      float tmax = -1e30f;
      #pragma unroll
      for (int r = 0; r < 4; r++){
        float v0 = keep[0][r] ? s0[r]*scale : -1e9f;
        float v1 = keep[1][r] ? s1[r]*scale : -1e9f;
        p[tm][r] = v0; p[tm][4 + r] = v1;
        tmax = fmaxf(tmax, fmaxf(v0, v1));
      }
      tmax = fmaxf(tmax, __shfl_xor(tmax, 16));
      tmax = fmaxf(tmax, __shfl_xor(tmax, 32));
      float mnew = fmaxf(mo[tm], tmax);
      float alpha = __expf(mo[tm] - mnew);
      mo[tm] = mnew;
      float ps = 0.f;
      #pragma unroll
      for (int i = 0; i < 8; i++){ p[tm][i] = __expf(p[tm][i] - mnew); ps += p[tm][i]; }
      ps += __shfl_xor(ps, 16);
      ps += __shfl_xor(ps, 32);
      li[tm] = li[tm]*alpha + ps;
      #pragma unroll
      for (int dt = 0; dt < 2; dt++){
        O[tm][dt][0] *= alpha; O[tm][dt][1] *= alpha;
        O[tm][dt][2] *= alpha; O[tm][dt][3] *= alpha;
      }
    }
    // Build PV B-fragment: lane needs P[q=lm (own q)][keys lq*8..+8] -> packed-bf16 lane permute.
    #pragma unroll
    for (int tm = 0; tm < 2; tm++){
      unsigned pk0[2], pk1[2];
      #pragma unroll
      for (int rr = 0; rr < 2; rr++){
        pk0[rr] = (unsigned)f2bu(p[tm][2*rr])     | ((unsigned)f2bu(p[tm][2*rr + 1]) << 16);
        pk1[rr] = (unsigned)f2bu(p[tm][4 + 2*rr]) | ((unsigned)f2bu(p[tm][4 + 2*rr + 1]) << 16);
      }
      union { unsigned u[4]; short8 s8; } pb;
      #pragma unroll
      for (int jj = 0; jj < 4; jj++){
        int src = (lqa*2 + (jj >> 1))*16 + lm;
        unsigned v0 = (unsigned)__shfl((int)pk0[jj & 1], src);
        unsigned v1 = (unsigned)__shfl((int)pk1[jj & 1], src);
        pb.u[jj] = hi ? v1 : v0;
      }
      #pragma unroll
      for (int dt = 0; dt < 2; dt++)
        O[tm][dt] = __builtin_amdgcn_mfma_f32_16x16x32_bf16(vf[dt], pb.s8, O[tm][dt], 0, 0, 0);
    }
  }
  // write per-wave partials; single barrier; flash-merge
  #pragma unroll
  for (int tm = 0; tm < 2; tm++){
    #pragma unroll
    for (int dt = 0; dt < 2; dt++)
      #pragma unroll
      for (int r = 0; r < 4; r++)
        OS[w][tm*16 + lm][dt*16 + lq*4 + r] = O[tm][dt][r];
    if (lq == 0){ mS[w][tm*16 + lm] = mo[tm]; lS[w][tm*16 + lm] = li[tm]; }
  }
  __syncthreads();
  int q = t >> 3, d0 = (t & 7)*4;
  float mm = fmaxf(fmaxf(mS[0][q], mS[1][q]), fmaxf(mS[2][q], mS[3][q]));
  float ll = 0.f, o0 = 0.f, o1 = 0.f, o2 = 0.f, o3 = 0.f;
  #pragma unroll
  for (int ww = 0; ww < 4; ww++){
    float f = __expf(mS[ww][q] - mm);
    ll += f*lS[ww][q];
    o0 += f*OS[ww][q][d0 + 0];
    o1 += f*OS[ww][q][d0 + 1];
    o2 += f*OS[ww][q][d0 + 2];
    o3 += f*OS[ww][q][d0 + 3];
  }
  int row = q0 + q;
  if (row < QN){
    float inv = 1.f/ll;
    bf16* dst = attn_b + (size_t)(n*QN + row)*DM + h*32 + d0;
    dst[0] = __float2bfloat16(o0*inv);
    dst[1] = __float2bfloat16(o1*inv);
    dst[2] = __float2bfloat16(o2*inv);
    dst[3] = __float2bfloat16(o3*inv);
  }
}

// ---------------- fused LN1 + offsets/attention-weight GEMV + sample coords ----------------
__global__ void __launch_bounds__(128) ln_off_attn_kernel(
    const float* __restrict__ lin, const float* __restrict__ g1, const float* __restrict__ b1,
    const float* __restrict__ og, const float* __restrict__ ref,
    const bf16* __restrict__ Woffb, const float* __restrict__ boff,
    const bf16* __restrict__ Wattnb, const float* __restrict__ battn,
    float* __restrict__ out2, float* __restrict__ locb, float* __restrict__ awb){
  int row = blockIdx.x, t = threadIdx.x, w = t >> 6, l = t & 63;
  __shared__ float a[DM];
  __shared__ float red[2];
  __shared__ float offL[64]; __shared__ float awL[32];
  float v0 = lin[(size_t)row*DM + t];
  float v1 = lin[(size_t)row*DM + t + 128];
  float s = v0 + v1;
  #pragma unroll
  for (int off = 1; off < 64; off <<= 1) s += __shfl_xor(s, off);
  if (l == 0) red[w] = s;
  __syncthreads();
  float mean = (red[0] + red[1])*(1.f/DM);
  float c0 = v0 - mean, c1 = v1 - mean;
  float ss = c0*c0 + c1*c1;
  #pragma unroll
  for (int off = 1; off < 64; off <<= 1) ss += __shfl_xor(ss, off);
  __syncthreads();
  if (l == 0) red[w] = ss;
  __syncthreads();
  float rstd = rsqrtf((red[0] + red[1])*(1.f/DM) + 1e-5f);
  float o0 = c0*rstd*g1[t] + b1[t];
  float o1 = c1*rstd*g1[t+128] + b1[t+128];
  out2[(size_t)row*DM + t]       = o0;
  out2[(size_t)row*DM + t + 128] = o1;
  a[t]       = o0 + og[(size_t)row*DM + t];
  a[t + 128] = o1 + og[(size_t)row*DM + t + 128];
  __syncthreads();
  if (t < 64){
    float acc = boff[t];
    for (int k = 0; k < DM; k++) acc += a[k]*bf2f(Woffb[k*64 + t]);
    offL[t] = acc;
  } else if (t < 96){
    int j = t - 64;
    float acc = battn[j];
    for (int k = 0; k < DM; k++) acc += a[k]*bf2f(Wattnb[k*32 + j]);
    awL[j] = acc;
  }
  __syncthreads();
  if (t < 64){
    int c = t & 1;
    float refv = ref[row*2 + c];
    locb[row*64 + t] = refv*200.0f + offL[t] - 0.5f;
  }
  if (t < 8){
    float m = -1e30f;
    #pragma unroll
    for (int p = 0; p < 4; p++) m = fmaxf(m, awL[t*4 + p]);
    float e[4]; float sm = 0.f;
    #pragma unroll
    for (int p = 0; p < 4; p++){ e[p] = __expf(awL[t*4 + p] - m); sm += e[p]; }
    #pragma unroll
    for (int p = 0; p < 4; p++) awb[row*32 + t*4 + p] = e[p]/sm;
  }
}

// ---------------- K6'': dedup'd bilinear gather + Wval projection, 4 rows/block --------
__global__ void __launch_bounds__(256) deform_proj_kernel(
    const float* __restrict__ bev, const float* __restrict__ locb,
    const float* __restrict__ awb, const bf16* __restrict__ WvalT,
    const float* __restrict__ bval, float* __restrict__ sampled){
  int t = threadIdx.x, l = t & 63, wvi = t >> 6;   // wave wvi owns row row0+wvi
  int row0 = blockIdx.x*RPB;
  int rowW = row0 + wvi;
  __shared__ float locS[RPB][64];
  __shared__ float awS[RPB][32];
  __shared__ int   pcS[RPB][128];      // packed (y<<16)|x, -1 = invalid
  __shared__ float wS[RPB][128];       // aw*wgt (0 if invalid)
  __shared__ float wtabS[RPB][8][16];  // per-head per-bbox-cell combined weight
  __shared__ int   cellListS[RPB][16];
  __shared__ int   ndS[RPB];           // #bbox cells; 0 = none valid; -1 = fallback
  __shared__ float wsumS[RPB][8];
  __shared__ float aggS[RPB][8][DM];   // 32 KB

  locS[wvi][l] = locb[(size_t)rowW*64 + l];
  if (l < 32) awS[wvi][l] = awb[(size_t)rowW*32 + l];

  int pk0[2]; float w0[2];
  #pragma unroll
  for (int i = 0; i < 2; i++){
    int e = l + i*64;
    int h = e >> 4, j = e & 15, p = j >> 2, c = j & 3, dx = c & 1, dy = c >> 1;
    float x = locS[wvi][h*8 + p*2], y = locS[wvi][h*8 + p*2 + 1];
    float aw = awS[wvi][h*4 + p];
    float x0f = floorf(x), y0f = floorf(y);
    float fx = x - x0f, fy = y - y0f;
    int xc = (int)x0f + dx, yc = (int)y0f + dy;
    float wg = (dx ? fx : 1.f - fx) * (dy ? fy : 1.f - fy);
    bool ok = (xc >= 0) && (xc < WBg) && (yc >= 0) && (yc < HBg);
    pk0[i] = ok ? ((yc << 16) | xc) : -1;
    w0[i]  = ok ? aw*wg : 0.f;
    pcS[wvi][e] = pk0[i];
    wS[wvi][e]  = w0[i];
  }

  int mnx = 0x7fff, mny = 0x7fff, mxx = -1, mxy = -1;
  #pragma unroll
  for (int i = 0; i < 2; i++){
    if (pk0[i] >= 0){
      int x = pk0[i] & 0xffff, y = pk0[i] >> 16;
      mnx = min(mnx, x); mxx = max(mxx, x);
      mny = min(mny, y); mxy = max(mxy, y);
    }
  }
  #pragma unroll
  for (int off = 32; off; off >>= 1){
    mnx = min(mnx, __shfl_xor(mnx, off));
    mxx = max(mxx, __shfl_xor(mxx, off));
    mny = min(mny, __shfl_xor(mny, off));
    mxy = max(mxy, __shfl_xor(mxy, off));
  }
  int nd, bw = 1;
  if (mxx < 0) nd = 0;
  else {
    bw = mxx - mnx + 1; int bh = mxy - mny + 1;
    nd = (bw <= 16 && bh <= 16 && bw*bh <= 16) ? bw*bh : -1;
  }
  if (l == 0) ndS[wvi] = nd;

  if (nd > 0){
    #pragma unroll
    for (int i = 0; i < 2; i++){
      int s = l + i*64;
      int h = s >> 4, ci = s & 15;
      if (ci < nd){
        int cy = mny + ci / bw, cx = mnx + ci % bw;
        int pk = (cy << 16) | cx;
        float w = 0.f;
        #pragma unroll
        for (int j = 0; j < 16; j++)
          if (pcS[wvi][h*16 + j] == pk) w += wS[wvi][h*16 + j];
        wtabS[wvi][h][ci] = w;
        if (h == 0) cellListS[wvi][ci] = cy*WBg + cx;
      }
    }
  }
  if (l < 8){
    float s = 0.f;
    #pragma unroll
    for (int j = 0; j < 16; j++) s += wS[wvi][l*16 + j];
    wsumS[wvi][l] = s;
  }
  __syncthreads();

  float agg[RPB][8];
  #pragma unroll
  for (int r = 0; r < RPB; r++)
    #pragma unroll
    for (int h = 0; h < 8; h++) agg[r][h] = 0.f;
  #pragma unroll
  for (int r = 0; r < RPB; r++){
    int n = (row0 + r)/QN;
    const float* bevn = bev + (size_t)n*NV*DM + t;
    int nd_r = ndS[r];
    if (nd_r >= 0){
      for (int ci = 0; ci < nd_r; ci++){
        float v = bevn[(size_t)cellListS[r][ci]*DM];
        #pragma unroll
        for (int h = 0; h < 8; h++) agg[r][h] += wtabS[r][h][ci]*v;
      }
    } else {
      #pragma unroll
      for (int h = 0; h < 8; h++){
        for (int j = 0; j < 16; j++){
          int pk = pcS[r][h*16 + j];
          if (pk >= 0){
            int cell = (pk >> 16)*WBg + (pk & 0xffff);
            agg[r][h] += wS[r][h*16 + j]*bevn[(size_t)cell*DM];
          }
        }
      }
    }
    #pragma unroll
    for (int h = 0; h < 8; h++) aggS[r][h][t] = agg[r][h];
  }
  __syncthreads();

  int h2 = t >> 5;
  const bf16* wrow = WvalT + (size_t)t*DM;
  float outv[RPB];
  float bvt = bval[t];
  #pragma unroll
  for (int r = 0; r < RPB; r++) outv[r] = wsumS[r][h2]*bvt;
  #pragma unroll 2
  for (int kb = 0; kb < 32; kb++){
    short8 wv8 = *(const short8*)(const void*)(wrow + kb*8);
    const bf16* wp = (const bf16*)&wv8;
    float wf[8];
    #pragma unroll
    for (int j = 0; j < 8; j++) wf[j] = bf2f(wp[j]);
    #pragma unroll
    for (int r = 0; r < RPB; r++){
      floatx4 a0 = *(floatx4*)&aggS[r][h2][kb*8];
      floatx4 a1 = *(floatx4*)&aggS[r][h2][kb*8 + 4];
      outv[r] += a0.x*wf[0] + a0.y*wf[1] + a0.z*wf[2] + a0.w*wf[3]
               + a1.x*wf[4] + a1.y*wf[5] + a1.z*wf[6] + a1.w*wf[7];
    }
  }
  #pragma unroll
  for (int r = 0; r < RPB; r++)
    sampled[(size_t)(row0 + r)*DM + t] = outv[r];
}

extern "C" void kernel_launch(void* const* d_in, const int* in_sizes, int n_in,
                              void* d_out, int out_size, void* d_ws, size_t ws_size,
                              hipStream_t stream) {
  const float* queries = (const float*)d_in[0];
  const float* bev     = (const float*)d_in[1];
  const float* ref     = (const float*)d_in[2];
  const float* og      = (const float*)d_in[3];
  const float* mask    = (const float*)d_in[4];
  const float* Wq = (const float*)d_in[5];  const float* bq = (const float*)d_in[6];
  const float* Wk = (const float*)d_in[7];  const float* bk = (const float*)d_in[8];
  const float* Wv = (const float*)d_in[9];  const float* bv = (const float*)d_in[10];
  const float* Wo = (const float*)d_in[11]; const float* bo = (const float*)d_in[12];
  const float* ln1g = (const float*)d_in[13]; const float* ln1b = (const float*)d_in[14];
  const float* Wval = (const float*)d_in[15]; const float* bval = (const float*)d_in[16];
  const float* Woff = (const float*)d_in[17]; const float* boff = (const float*)d_in[18];
  const float* Wattn = (const float*)d_in[19]; const float* battn = (const float*)d_in[20];
  const float* Wdo = (const float*)d_in[21]; const float* bdo = (const float*)d_in[22];
  const float* ln2g = (const float*)d_in[23]; const float* ln2b = (const float*)d_in[24];
  const float* W1 = (const float*)d_in[25]; const float* b1 = (const float*)d_in[26];
  const float* W2 = (const float*)d_in[27]; const float* b2 = (const float*)d_in[28];
  const float* ln3g = (const float*)d_in[29]; const float* ln3b = (const float*)d_in[30];

  char* base = (char*)d_ws;
  bf16*  WqkT   = (bf16*)base;  base += 262144;   // [512][256]
  bf16*  WvT    = (bf16*)base;  base += 131072;
  bf16*  WoT    = (bf16*)base;  base += 131072;
  bf16*  WvalT  = (bf16*)base;  base += 131072;
  bf16*  WdoT   = (bf16*)base;  base += 131072;
  bf16*  W1T    = (bf16*)base;  base += 262144;   // [512][256]
  bf16*  W2T    = (bf16*)base;  base += 262144;   // [256][512]
  bf16*  Woffb  = (bf16*)base;  base += 32768;
  bf16*  Wattnb = (bf16*)base;  base += 16384;
  bf16*  qh_b   = (bf16*)base;  base += 1843200;
  bf16*  kh_b   = (bf16*)base;  base += 1843200;
  bf16*  vt     = (bf16*)base;  base += 1966080;  // [1024][960]
  bf16*  attn_b = (bf16*)base;  base += 1843200;
  float* out2   = (float*)base; base += 3686400;
  float* sampled= (float*)base; base += 3686400;
  bf16*  out4_b = (bf16*)base;  base += 1843200;
  bf16*  hid    = (bf16*)base;  base += 3686400;  // [3600][512] bf16
  float* locb   = (float*)base; base += 921600;
  float* awb    = (float*)base; base += 460800;
  float* lin    = (float*)base; base += 3686400;  // shared pre-LN buffer

  // zero vt pad columns (keys 900..959) so split-K PV never multiplies garbage
  hipMemsetAsync(vt, 0, 1966080, stream);

  cvtAll<<<736, 256, 0, stream>>>(Wq, Wk, Wv, Wo, Wval, Wdo, W1, W2, Woff, Wattn,
                                  WqkT, WvT, WoT, WvalT, WdoT, W1T, W2T, Woffb, Wattnb);
  // fused q,k,v projections
  qkv_mm_kernel<<<dim3(113, 12), 128, 0, stream>>>(queries, og, WqkT, WvT, bq, bk, bv,
                                                   qh_b, kh_b, vt);
  mha_flash<<<dim3(29, HH, NB), 256, 0, stream>>>(qh_b, kh_b, vt, mask, attn_b);
  // Wo GEMM + queries residual -> lin
  mm2_kernel<2,256,2><<<dim3(113,4), 128, 0, stream>>>(attn_b, WoT, bo, queries, nullptr,
                                                       lin, nullptr);
  // LN1 + off/attn GEMV fused (aug stays in LDS)
  ln_off_attn_kernel<<<MT, 128, 0, stream>>>(lin, ln1g, ln1b, og, ref,
                                             Woffb, boff, Wattnb, battn,
                                             out2, locb, awb);
  deform_proj_kernel<<<MT/RPB, 256, 0, stream>>>(bev, locb, awb, WvalT, bval, sampled);
  // Wdo GEMM * mask + out2 residual -> lin
  mm2_kernel<0,256,3><<<dim3(113,4), 128, 0, stream>>>(sampled, WdoT, bdo, out2, mask,
                                                       lin, nullptr);
  ln_kernel<1><<<900, 256, 0, stream>>>(lin, ln2g, ln2b, out4_b);
  // FFN1 + relu -> hid bf16
  mm2_kernel<2,256,4><<<dim3(113,8), 128, 0, stream>>>(out4_b, W1T, b1, nullptr, nullptr,
                                                       hid, nullptr);
  // FFN2 + out4 residual -> lin
  mm2_kernel<2,512,5><<<dim3(113,4), 128, 0, stream>>>(hid, W2T, b2, nullptr, nullptr,
                                                       lin, out4_b);
  ln_kernel<2><<<900, 256, 0, stream>>>(lin, ln3g, ln3b, (float*)d_out);
}

// Round 19
// 390.260 us; speedup vs baseline: 3.2614x; 1.0102x over previous
//
#include <hip/hip_runtime.h>
#include <hip/hip_bf16.h>
#include <cstddef>

#define NB  4
#define QN  900
#define DM  256
#define HH  8
#define HD  32
#define PP  4
#define HBg 200
#define WBg 200
#define FFD 512
#define NV  (HBg*WBg)   // 40000 bev cells
#define RPB 4           // deform: queries (rows) per block
#define MT  3600        // total rows

typedef __hip_bfloat16 bf16;
typedef __attribute__((ext_vector_type(8))) short short8;
typedef __attribute__((ext_vector_type(4))) float floatx4;
typedef __attribute__((ext_vector_type(16))) float floatx16;

__device__ __forceinline__ float bf2f(bf16 x){ return __bfloat162float(x); }
__device__ __forceinline__ unsigned short f2bu(float f){
  bf16 h = __float2bfloat16(f);
  return *(unsigned short*)&h;
}

// ---------------- K0: fused transpose+convert of all GEMM weights + Woff/Wattn ----------------
__global__ void __launch_bounds__(256) cvtAll(
    const float* __restrict__ Wq, const float* __restrict__ Wk,
    const float* __restrict__ Wv, const float* __restrict__ Wo,
    const float* __restrict__ Wval, const float* __restrict__ Wdo,
    const float* __restrict__ W1, const float* __restrict__ W2,
    const float* __restrict__ Woff, const float* __restrict__ Wattn,
    bf16* __restrict__ WqkT, bf16* __restrict__ WvT, bf16* __restrict__ WoT,
    bf16* __restrict__ WvalT, bf16* __restrict__ WdoT,
    bf16* __restrict__ W1T, bf16* __restrict__ W2T,
    bf16* __restrict__ Woffb, bf16* __restrict__ Wattnb){
  int b = blockIdx.x;
  if (b >= 640){
    int i = (b - 640)*256 + threadIdx.x;
    if (i < 16384) Woffb[i] = __float2bfloat16(Woff[i]);
    else if (i < 24576) Wattnb[i - 16384] = __float2bfloat16(Wattn[i - 16384]);
    return;
  }
  const float* S; bf16* D; int K, N, tile;
  if      (b <  64){ S=Wq;   D=WqkT;        K=256; N=256; tile=b; }
  else if (b < 128){ S=Wk;   D=WqkT+65536;  K=256; N=256; tile=b-64; }
  else if (b < 192){ S=Wv;   D=WvT;         K=256; N=256; tile=b-128; }
  else if (b < 256){ S=Wo;   D=WoT;         K=256; N=256; tile=b-192; }
  else if (b < 320){ S=Wval; D=WvalT;       K=256; N=256; tile=b-256; }
  else if (b < 384){ S=Wdo;  D=WdoT;        K=256; N=256; tile=b-320; }
  else if (b < 512){ S=W1;   D=W1T;         K=256; N=512; tile=b-384; }
  else             { S=W2;   D=W2T;         K=512; N=256; tile=b-512; }
  int ntn = N >> 5;
  int k0 = (tile / ntn) << 5, n0 = (tile % ntn) << 5;
  __shared__ float tl[32][33];
  for (int i = threadIdx.x; i < 1024; i += 256){
    int r = i >> 5, c = i & 31;
    tl[r][c] = S[(size_t)(k0 + r)*N + n0 + c];
  }
  __syncthreads();
  for (int i = threadIdx.x; i < 1024; i += 256){
    int r = i >> 5, c = i & 31;
    D[(size_t)(n0 + r)*K + k0 + c] = __float2bfloat16(tl[c][r]);
  }
}

// ---------------- fused q/k/v projection GEMM: 32 rows x 64 cols, BK=64 ----------------
__global__ void __launch_bounds__(128) qkv_mm_kernel(
    const float* __restrict__ queries, const float* __restrict__ og,
    const bf16* __restrict__ WqkT, const bf16* __restrict__ WvT,
    const float* __restrict__ bq, const float* __restrict__ bk, const float* __restrict__ bv,
    bf16* __restrict__ qh_b, bf16* __restrict__ kh_b, bf16* __restrict__ vt_){
  int t = threadIdx.x, l = t & 63, w = t >> 6, lm = l & 15, lq = l >> 4;
  int row0 = blockIdx.x*32;
  bool isv = blockIdx.y >= 8;
  int col0 = (isv ? (int)blockIdx.y - 8 : (int)blockIdx.y)*64;
  const bf16* B = isv ? WvT : WqkT;
  __shared__ __align__(16) short As[32*72];
  floatx4 acc[2][2];
  #pragma unroll
  for (int tm = 0; tm < 2; tm++)
    #pragma unroll
    for (int tn = 0; tn < 2; tn++) acc[tm][tn] = (floatx4){0,0,0,0};

  for (int kt = 0; kt < 4; kt++){
    int k0 = kt*64;
    __syncthreads();
    #pragma unroll
    for (int i = 0; i < 4; i++){
      int s = t + i*128;           // 512 float4 slots
      int r = s >> 4, kq = s & 15;
      int rr = row0 + r; if (rr > MT-1) rr = MT-1;
      float4 v = *(const float4*)(queries + (size_t)rr*DM + k0 + kq*4);
      if (!isv){
        float4 u = *(const float4*)(og + (size_t)rr*DM + k0 + kq*4);
        v.x += u.x; v.y += u.y; v.z += u.z; v.w += u.w;
      }
      unsigned int p0 = (unsigned int)f2bu(v.x) | ((unsigned int)f2bu(v.y) << 16);
      unsigned int p1 = (unsigned int)f2bu(v.z) | ((unsigned int)f2bu(v.w) << 16);
      uint2 pk; pk.x = p0; pk.y = p1;
      *(uint2*)&As[r*72 + kq*4] = pk;
    }
    __syncthreads();
    short8 bfr[2][2];
    #pragma unroll
    for (int tn = 0; tn < 2; tn++)
      #pragma unroll
      for (int ks = 0; ks < 2; ks++)
        bfr[tn][ks] = *(const short8*)(const void*)(B + (size_t)(col0 + w*32 + tn*16 + lm)*DM + k0 + ks*32 + lq*8);
    #pragma unroll
    for (int tm = 0; tm < 2; tm++)
      #pragma unroll
      for (int ks = 0; ks < 2; ks++){
        short8 af = *(short8*)&As[(tm*16 + lm)*72 + ks*32 + lq*8];
        #pragma unroll
        for (int tn = 0; tn < 2; tn++)
          acc[tm][tn] = __builtin_amdgcn_mfma_f32_16x16x32_bf16(af, bfr[tn][ks], acc[tm][tn], 0, 0, 0);
      }
  }
  #pragma unroll
  for (int tm = 0; tm < 2; tm++){
    int grow = row0 + tm*16 + lq*4;
    #pragma unroll
    for (int tn = 0; tn < 2; tn++){
      int col = col0 + w*32 + tn*16 + lm;
      #pragma unroll
      for (int r = 0; r < 4; r++){
        int row = grow + r;
        if (row < MT){
          float v = acc[tm][tn][r];
          if (!isv){
            float bb = (col < 256) ? bq[col] : bk[col - 256];
            bf16 o = __float2bfloat16(v + bb);
            if (col < 256) qh_b[(size_t)row*DM + col] = o;
            else           kh_b[(size_t)row*DM + col - 256] = o;
          } else {
            int n = row/QN, q = row - n*QN;
            int h = col >> 5, d = col & 31;
            vt_[((size_t)((n*HH + h)*HD + d))*960 + q] = __float2bfloat16(v + bv[col]);
          }
        }
      }
    }
  }
}

// ---------------- unified MFMA GEMM v2: 32 rows x 64 cols per block, BK=64 ----------------
// AM: 0 = fp32 A, 2 = bf16 A.
// EPI: 2 +bias+res fp32 (Wo), 3 (+bias)*mask+res fp32 (Wdo),
//      4 relu bf16 stride FFD (W1), 5 +bias+bf16res fp32 (W2)
template<int AM, int KD, int EPI>
__global__ void __launch_bounds__(128) mm2_kernel(
    const void* __restrict__ Aptr,
    const bf16* __restrict__ B, const float* __restrict__ bias,
    const float* __restrict__ res, const float* __restrict__ mask,
    void* __restrict__ out, void* __restrict__ out2nd){
  int t = threadIdx.x, l = t & 63, w = t >> 6, lm = l & 15, lq = l >> 4;
  int row0 = blockIdx.x*32;
  int col0 = blockIdx.y*64;
  __shared__ __align__(16) short As[32*72];
  floatx4 acc[2][2];
  #pragma unroll
  for (int tm = 0; tm < 2; tm++)
    #pragma unroll
    for (int tn = 0; tn < 2; tn++) acc[tm][tn] = (floatx4){0,0,0,0};

  for (int kt = 0; kt < KD/64; kt++){
    int k0 = kt*64;
    __syncthreads();
    if (AM == 2){
      #pragma unroll
      for (int i = 0; i < 2; i++){
        int s = t + i*128;           // 256 short8 slots
        int r = s >> 3, c = s & 7;
        int rr = row0 + r; if (rr > MT-1) rr = MT-1;
        *(short8*)&As[r*72 + c*8] =
          *(const short8*)(const void*)((const bf16*)Aptr + (size_t)rr*KD + k0 + c*8);
      }
    } else {
      #pragma unroll
      for (int i = 0; i < 4; i++){
        int s = t + i*128;
        int r = s >> 4, kq = s & 15;
        int rr = row0 + r; if (rr > MT-1) rr = MT-1;
        float4 v = *(const float4*)((const float*)Aptr + (size_t)rr*KD + k0 + kq*4);
        unsigned int p0 = (unsigned int)f2bu(v.x) | ((unsigned int)f2bu(v.y) << 16);
        unsigned int p1 = (unsigned int)f2bu(v.z) | ((unsigned int)f2bu(v.w) << 16);
        uint2 pk; pk.x = p0; pk.y = p1;
        *(uint2*)&As[r*72 + kq*4] = pk;
      }
    }
    __syncthreads();
    short8 bfr[2][2];
    #pragma unroll
    for (int tn = 0; tn < 2; tn++)
      #pragma unroll
      for (int ks = 0; ks < 2; ks++)
        bfr[tn][ks] = *(const short8*)(const void*)(B + (size_t)(col0 + w*32 + tn*16 + lm)*KD + k0 + ks*32 + lq*8);
    #pragma unroll
    for (int tm = 0; tm < 2; tm++)
      #pragma unroll
      for (int ks = 0; ks < 2; ks++){
        short8 af = *(short8*)&As[(tm*16 + lm)*72 + ks*32 + lq*8];
        #pragma unroll
        for (int tn = 0; tn < 2; tn++)
          acc[tm][tn] = __builtin_amdgcn_mfma_f32_16x16x32_bf16(af, bfr[tn][ks], acc[tm][tn], 0, 0, 0);
      }
  }
  // C layout: col = lane&15, row = (lane>>4)*4 + reg
  #pragma unroll
  for (int tm = 0; tm < 2; tm++){
    int grow = row0 + tm*16 + lq*4;
    #pragma unroll
    for (int tn = 0; tn < 2; tn++){
      int col = col0 + w*32 + tn*16 + lm;
      #pragma unroll
      for (int r = 0; r < 4; r++){
        int row = grow + r;
        if (row < MT){
          float v = acc[tm][tn][r];
          if (EPI == 2){
            ((float*)out)[(size_t)row*DM + col] = v + bias[col] + res[(size_t)row*DM + col];
          } else if (EPI == 3){
            ((float*)out)[(size_t)row*DM + col] = (v + bias[col])*mask[row] + res[(size_t)row*DM + col];
          } else if (EPI == 4){
            ((bf16*)out)[(size_t)row*FFD + col] = __float2bfloat16(fmaxf(v + bias[col], 0.f));
          } else {
            ((float*)out)[(size_t)row*DM + col] = v + bias[col] + bf2f(((const bf16*)out2nd)[(size_t)row*DM + col]);
          }
        }
      }
    }
  }
}

// ---------------- LN: row per wave, shuffle reduce. MODE 1: ->bf16; 2: ->fp32
template<int MODE>
__global__ void __launch_bounds__(256) ln_kernel(
    const float* __restrict__ lin, const float* __restrict__ g, const float* __restrict__ b,
    void* __restrict__ o2){
  int wv = threadIdx.x >> 6, l = threadIdx.x & 63;
  int row = blockIdx.x*4 + wv;
  floatx4 v = *(const floatx4*)(lin + (size_t)row*DM + l*4);
  float s = v.x + v.y + v.z + v.w;
  #pragma unroll
  for (int off = 1; off < 64; off <<= 1) s += __shfl_xor(s, off);
  float mean = s*(1.f/DM);
  floatx4 c; c.x = v.x-mean; c.y = v.y-mean; c.z = v.z-mean; c.w = v.w-mean;
  float ss = c.x*c.x + c.y*c.y + c.z*c.z + c.w*c.w;
  #pragma unroll
  for (int off = 1; off < 64; off <<= 1) ss += __shfl_xor(ss, off);
  float rstd = rsqrtf(ss*(1.f/DM) + 1e-5f);
  floatx4 gv = *(const floatx4*)(g + l*4);
  floatx4 bv = *(const floatx4*)(b + l*4);
  floatx4 o;
  o.x = c.x*rstd*gv.x + bv.x; o.y = c.y*rstd*gv.y + bv.y;
  o.z = c.z*rstd*gv.z + bv.z; o.w = c.w*rstd*gv.w + bv.w;
  if (MODE == 1){
    bf16* d = (bf16*)o2 + (size_t)row*DM + l*4;
    d[0] = __float2bfloat16(o.x); d[1] = __float2bfloat16(o.y);
    d[2] = __float2bfloat16(o.z); d[3] = __float2bfloat16(o.w);
  } else {
    *(floatx4*)((float*)o2 + (size_t)row*DM + l*4) = o;
  }
}

// ---------------- K2'': split-K flash MHA, 32x32 swapped-operand MFMA ----------------
__global__ void __launch_bounds__(256) mha_flash(const bf16* __restrict__ qh_b,
                                                 const bf16* __restrict__ kh_b,
                                                 const bf16* __restrict__ vt,
                                                 const float* __restrict__ mask,
                                                 bf16* __restrict__ attn_b){
  int qt = blockIdx.x, h = blockIdx.y, n = blockIdx.z;
  int t = threadIdx.x, l = t & 63, w = t >> 6;
  int lc = l & 31, H = l >> 5;
  int q0 = qt*32;
  const float scale = 0.17677669529663687f;
  __shared__ float mS[4][32];
  __shared__ float lS[4][32];
  __shared__ float OS[4][32][33];

  // Q B-fragment: col=q=lc, k-dim d = c*16 + H*8 + j
  short8 qf[2];
  {
    int qr = q0 + lc; if (qr > QN-1) qr = QN-1;
    const bf16* qp = qh_b + (size_t)(n*QN + qr)*DM + h*32 + H*8;
    qf[0] = *(const short8*)(const void*)(qp);
    qf[1] = *(const short8*)(const void*)(qp + 16);
  }
  floatx16 O;
  #pragma unroll
  for (int r = 0; r < 16; r++) O[r] = 0.f;
  float mo = -1e30f, li = 0.f;

  const bf16*  kbase = kh_b + (size_t)n*QN*DM + h*32;
  const bf16*  vbase = vt + (size_t)((n*HH + h)*HD)*960;
  const float* mbase = mask + (size_t)n*QN;

  for (int g = w; g < 29; g += 4){
    int k0 = g*32;
    short8 kf[2];
    {
      int kr = k0 + lc; if (kr > QN-1) kr = QN-1;
      const bf16* kp = kbase + (size_t)kr*DM + H*8;
      kf[0] = *(const short8*)(const void*)(kp);
      kf[1] = *(const short8*)(const void*)(kp + 16);
    }
    short8 vf[2];
    {
      const bf16* vp = vbase + (size_t)lc*960 + k0 + H*8;
      vf[0] = *(const short8*)(const void*)(vp);
      vf[1] = *(const short8*)(const void*)(vp + 16);
    }
    int kk = k0 + lc, kc = kk > QN-1 ? QN-1 : kk;
    bool mykeep = (kk < QN) && (mbase[kc] > 0.f);
    unsigned long long kb = __ballot(mykeep);

    floatx16 Z;
    #pragma unroll
    for (int r = 0; r < 16; r++) Z[r] = 0.f;
    floatx16 S = __builtin_amdgcn_mfma_f32_32x32x16_bf16(kf[0], qf[0], Z, 0, 0, 0);
    S = __builtin_amdgcn_mfma_f32_32x32x16_bf16(kf[1], qf[1], S, 0, 0, 0);

    // C layout: row(key) = (r&3) + 4H + 8*(r>>2), col(q) = lc
    float p[16]; float tmax = -1e30f;
    #pragma unroll
    for (int r = 0; r < 16; r++){
      int key = (r & 3) + 4*H + 8*(r >> 2);
      bool keep = (kb >> key) & 1ull;
      float v = keep ? S[r]*scale : -1e9f;
      p[r] = v; tmax = fmaxf(tmax, v);
    }
    tmax = fmaxf(tmax, __shfl_xor(tmax, 32));
    float mnew = fmaxf(mo, tmax);
    float alpha = __expf(mo - mnew);
    mo = mnew;
    float ps = 0.f;
    #pragma unroll
    for (int r = 0; r < 16; r++){ p[r] = __expf(p[r] - mnew); ps += p[r]; }
    ps += __shfl_xor(ps, 32);
    li = li*alpha + ps;
    #pragma unroll
    for (int r = 0; r < 16; r++) O[r] *= alpha;

    // PV: B = P[key][q]; per chunk c keys 16c+8H+{0..7}: own half + partner (lane^32) half
    #pragma unroll
    for (int c = 0; c < 2; c++){
      unsigned w0 = (unsigned)f2bu(p[8*c+0]) | ((unsigned)f2bu(p[8*c+1]) << 16);
      unsigned w1 = (unsigned)f2bu(p[8*c+2]) | ((unsigned)f2bu(p[8*c+3]) << 16);
      unsigned w2 = (unsigned)f2bu(p[8*c+4]) | ((unsigned)f2bu(p[8*c+5]) << 16);
      unsigned w3 = (unsigned)f2bu(p[8*c+6]) | ((unsigned)f2bu(p[8*c+7]) << 16);
      unsigned x0 = (unsigned)__shfl_xor((int)w0, 32);
      unsigned x1 = (unsigned)__shfl_xor((int)w1, 32);
      unsigned x2 = (unsigned)__shfl_xor((int)w2, 32);
      unsigned x3 = (unsigned)__shfl_xor((int)w3, 32);
      union { unsigned u[4]; short8 s8; } pb;
      if (H == 0){ pb.u[0] = w0; pb.u[1] = w1; pb.u[2] = x0; pb.u[3] = x1; }
      else       { pb.u[0] = x2; pb.u[1] = x3; pb.u[2] = w2; pb.u[3] = w3; }
      O = __builtin_amdgcn_mfma_f32_32x32x16_bf16(vf[c], pb.s8, O, 0, 0, 0);
    }
  }
  // write per-wave partials (O^T: col=q=lc, row=d=(r&3)+4H+8*(r>>2)); single barrier; merge
  #pragma unroll
  for (int r = 0; r < 16; r++){
    int d = (r & 3) + 4*H + 8*(r >> 2);
    OS[w][lc][d] = O[r];
  }
  if (l < 32){ mS[w][lc] = mo; lS[w][lc] = li; }
  __syncthreads();
  int q = t >> 3, d0 = (t & 7)*4;
  float mm = fmaxf(fmaxf(mS[0][q], mS[1][q]), fmaxf(mS[2][q], mS[3][q]));
  float ll = 0.f, o0 = 0.f, o1 = 0.f, o2 = 0.f, o3 = 0.f;
  #pragma unroll
  for (int ww = 0; ww < 4; ww++){
    float f = __expf(mS[ww][q] - mm);
    ll += f*lS[ww][q];
    o0 += f*OS[ww][q][d0 + 0];
    o1 += f*OS[ww][q][d0 + 1];
    o2 += f*OS[ww][q][d0 + 2];
    o3 += f*OS[ww][q][d0 + 3];
  }
  int row = q0 + q;
  if (row < QN){
    float inv = 1.f/ll;
    bf16* dst = attn_b + (size_t)(n*QN + row)*DM + h*32 + d0;
    dst[0] = __float2bfloat16(o0*inv);
    dst[1] = __float2bfloat16(o1*inv);
    dst[2] = __float2bfloat16(o2*inv);
    dst[3] = __float2bfloat16(o3*inv);
  }
}

// ---------------- fused LN1 + offsets/attention-weight GEMV + sample coords ----------------
__global__ void __launch_bounds__(128) ln_off_attn_kernel(
    const float* __restrict__ lin, const float* __restrict__ g1, const float* __restrict__ b1,
    const float* __restrict__ og, const float* __restrict__ ref,
    const bf16* __restrict__ Woffb, const float* __restrict__ boff,
    const bf16* __restrict__ Wattnb, const float* __restrict__ battn,
    float* __restrict__ out2, float* __restrict__ locb, float* __restrict__ awb){
  int row = blockIdx.x, t = threadIdx.x, w = t >> 6, l = t & 63;
  __shared__ float a[DM];
  __shared__ float red[2];
  __shared__ float offL[64]; __shared__ float awL[32];
  float v0 = lin[(size_t)row*DM + t];
  float v1 = lin[(size_t)row*DM + t + 128];
  float s = v0 + v1;
  #pragma unroll
  for (int off = 1; off < 64; off <<= 1) s += __shfl_xor(s, off);
  if (l == 0) red[w] = s;
  __syncthreads();
  float mean = (red[0] + red[1])*(1.f/DM);
  float c0 = v0 - mean, c1 = v1 - mean;
  float ss = c0*c0 + c1*c1;
  #pragma unroll
  for (int off = 1; off < 64; off <<= 1) ss += __shfl_xor(ss, off);
  __syncthreads();
  if (l == 0) red[w] = ss;
  __syncthreads();
  float rstd = rsqrtf((red[0] + red[1])*(1.f/DM) + 1e-5f);
  float o0 = c0*rstd*g1[t] + b1[t];
  float o1 = c1*rstd*g1[t+128] + b1[t+128];
  out2[(size_t)row*DM + t]       = o0;
  out2[(size_t)row*DM + t + 128] = o1;
  a[t]       = o0 + og[(size_t)row*DM + t];
  a[t + 128] = o1 + og[(size_t)row*DM + t + 128];
  __syncthreads();
  if (t < 64){
    float acc = boff[t];
    for (int k = 0; k < DM; k++) acc += a[k]*bf2f(Woffb[k*64 + t]);
    offL[t] = acc;
  } else if (t < 96){
    int j = t - 64;
    float acc = battn[j];
    for (int k = 0; k < DM; k++) acc += a[k]*bf2f(Wattnb[k*32 + j]);
    awL[j] = acc;
  }
  __syncthreads();
  if (t < 64){
    int c = t & 1;
    float refv = ref[row*2 + c];
    locb[row*64 + t] = refv*200.0f + offL[t] - 0.5f;
  }
  if (t < 8){
    float m = -1e30f;
    #pragma unroll
    for (int p = 0; p < 4; p++) m = fmaxf(m, awL[t*4 + p]);
    float e[4]; float sm = 0.f;
    #pragma unroll
    for (int p = 0; p < 4; p++){ e[p] = __expf(awL[t*4 + p] - m); sm += e[p]; }
    #pragma unroll
    for (int p = 0; p < 4; p++) awb[row*32 + t*4 + p] = e[p]/sm;
  }
}

// ---------------- K6'': dedup'd bilinear gather + Wval projection, 4 rows/block --------
__global__ void __launch_bounds__(256) deform_proj_kernel(
    const float* __restrict__ bev, const float* __restrict__ locb,
    const float* __restrict__ awb, const bf16* __restrict__ WvalT,
    const float* __restrict__ bval, float* __restrict__ sampled){
  int t = threadIdx.x, l = t & 63, wvi = t >> 6;   // wave wvi owns row row0+wvi
  int row0 = blockIdx.x*RPB;
  int rowW = row0 + wvi;
  __shared__ float locS[RPB][64];
  __shared__ float awS[RPB][32];
  __shared__ int   pcS[RPB][128];      // packed (y<<16)|x, -1 = invalid
  __shared__ float wS[RPB][128];       // aw*wgt (0 if invalid)
  __shared__ float wtabS[RPB][8][16];  // per-head per-bbox-cell combined weight
  __shared__ int   cellListS[RPB][16];
  __shared__ int   ndS[RPB];           // #bbox cells; 0 = none valid; -1 = fallback
  __shared__ float wsumS[RPB][8];
  __shared__ float aggS[RPB][8][DM];   // 32 KB

  locS[wvi][l] = locb[(size_t)rowW*64 + l];
  if (l < 32) awS[wvi][l] = awb[(size_t)rowW*32 + l];

  int pk0[2]; float w0[2];
  #pragma unroll
  for (int i = 0; i < 2; i++){
    int e = l + i*64;
    int h = e >> 4, j = e & 15, p = j >> 2, c = j & 3, dx = c & 1, dy = c >> 1;
    float x = locS[wvi][h*8 + p*2], y = locS[wvi][h*8 + p*2 + 1];
    float aw = awS[wvi][h*4 + p];
    float x0f = floorf(x), y0f = floorf(y);
    float fx = x - x0f, fy = y - y0f;
    int xc = (int)x0f + dx, yc = (int)y0f + dy;
    float wg = (dx ? fx : 1.f - fx) * (dy ? fy : 1.f - fy);
    bool ok = (xc >= 0) && (xc < WBg) && (yc >= 0) && (yc < HBg);
    pk0[i] = ok ? ((yc << 16) | xc) : -1;
    w0[i]  = ok ? aw*wg : 0.f;
    pcS[wvi][e] = pk0[i];
    wS[wvi][e]  = w0[i];
  }

  int mnx = 0x7fff, mny = 0x7fff, mxx = -1, mxy = -1;
  #pragma unroll
  for (int i = 0; i < 2; i++){
    if (pk0[i] >= 0){
      int x = pk0[i] & 0xffff, y = pk0[i] >> 16;
      mnx = min(mnx, x); mxx = max(mxx, x);
      mny = min(mny, y); mxy = max(mxy, y);
    }
  }
  #pragma unroll
  for (int off = 32; off; off >>= 1){
    mnx = min(mnx, __shfl_xor(mnx, off));
    mxx = max(mxx, __shfl_xor(mxx, off));
    mny = min(mny, __shfl_xor(mny, off));
    mxy = max(mxy, __shfl_xor(mxy, off));
  }
  int nd, bw = 1;
  if (mxx < 0) nd = 0;
  else {
    bw = mxx - mnx + 1; int bh = mxy - mny + 1;
    nd = (bw <= 16 && bh <= 16 && bw*bh <= 16) ? bw*bh : -1;
  }
  if (l == 0) ndS[wvi] = nd;

  if (nd > 0){
    #pragma unroll
    for (int i = 0; i < 2; i++){
      int s = l + i*64;
      int h = s >> 4, ci = s & 15;
      if (ci < nd){
        int cy = mny + ci / bw, cx = mnx + ci % bw;
        int pk = (cy << 16) | cx;
        float w = 0.f;
        #pragma unroll
        for (int j = 0; j < 16; j++)
          if (pcS[wvi][h*16 + j] == pk) w += wS[wvi][h*16 + j];
        wtabS[wvi][h][ci] = w;
        if (h == 0) cellListS[wvi][ci] = cy*WBg + cx;
      }
    }
  }
  if (l < 8){
    float s = 0.f;
    #pragma unroll
    for (int j = 0; j < 16; j++) s += wS[wvi][l*16 + j];
    wsumS[wvi][l] = s;
  }
  __syncthreads();

  float agg[RPB][8];
  #pragma unroll
  for (int r = 0; r < RPB; r++)
    #pragma unroll
    for (int h = 0; h < 8; h++) agg[r][h] = 0.f;
  #pragma unroll
  for (int r = 0; r < RPB; r++){
    int n = (row0 + r)/QN;
    const float* bevn = bev + (size_t)n*NV*DM + t;
    int nd_r = ndS[r];
    if (nd_r >= 0){
      for (int ci = 0; ci < nd_r; ci++){
        float v = bevn[(size_t)cellListS[r][ci]*DM];
        #pragma unroll
        for (int h = 0; h < 8; h++) agg[r][h] += wtabS[r][h][ci]*v;
      }
    } else {
      #pragma unroll
      for (int h = 0; h < 8; h++){
        for (int j = 0; j < 16; j++){
          int pk = pcS[r][h*16 + j];
          if (pk >= 0){
            int cell = (pk >> 16)*WBg + (pk & 0xffff);
            agg[r][h] += wS[r][h*16 + j]*bevn[(size_t)cell*DM];
          }
        }
      }
    }
    #pragma unroll
    for (int h = 0; h < 8; h++) aggS[r][h][t] = agg[r][h];
  }
  __syncthreads();

  int h2 = t >> 5;
  const bf16* wrow = WvalT + (size_t)t*DM;
  float outv[RPB];
  float bvt = bval[t];
  #pragma unroll
  for (int r = 0; r < RPB; r++) outv[r] = wsumS[r][h2]*bvt;
  #pragma unroll 2
  for (int kb = 0; kb < 32; kb++){
    short8 wv8 = *(const short8*)(const void*)(wrow + kb*8);
    const bf16* wp = (const bf16*)&wv8;
    float wf[8];
    #pragma unroll
    for (int j = 0; j < 8; j++) wf[j] = bf2f(wp[j]);
    #pragma unroll
    for (int r = 0; r < RPB; r++){
      floatx4 a0 = *(floatx4*)&aggS[r][h2][kb*8];
      floatx4 a1 = *(floatx4*)&aggS[r][h2][kb*8 + 4];
      outv[r] += a0.x*wf[0] + a0.y*wf[1] + a0.z*wf[2] + a0.w*wf[3]
               + a1.x*wf[4] + a1.y*wf[5] + a1.z*wf[6] + a1.w*wf[7];
    }
  }
  #pragma unroll
  for (int r = 0; r < RPB; r++)
    sampled[(size_t)(row0 + r)*DM + t] = outv[r];
}

extern "C" void kernel_launch(void* const* d_in, const int* in_sizes, int n_in,
                              void* d_out, int out_size, void* d_ws, size_t ws_size,
                              hipStream_t stream) {
  const float* queries = (const float*)d_in[0];
  const float* bev     = (const float*)d_in[1];
  const float* ref     = (const float*)d_in[2];
  const float* og      = (const float*)d_in[3];
  const float* mask    = (const float*)d_in[4];
  const float* Wq = (const float*)d_in[5];  const float* bq = (const float*)d_in[6];
  const float* Wk = (const float*)d_in[7];  const float* bk = (const float*)d_in[8];
  const float* Wv = (const float*)d_in[9];  const float* bv = (const float*)d_in[10];
  const float* Wo = (const float*)d_in[11]; const float* bo = (const float*)d_in[12];
  const float* ln1g = (const float*)d_in[13]; const float* ln1b = (const float*)d_in[14];
  const float* Wval = (const float*)d_in[15]; const float* bval = (const float*)d_in[16];
  const float* Woff = (const float*)d_in[17]; const float* boff = (const float*)d_in[18];
  const float* Wattn = (const float*)d_in[19]; const float* battn = (const float*)d_in[20];
  const float* Wdo = (const float*)d_in[21]; const float* bdo = (const float*)d_in[22];
  const float* ln2g = (const float*)d_in[23]; const float* ln2b = (const float*)d_in[24];
  const float* W1 = (const float*)d_in[25]; const float* b1 = (const float*)d_in[26];
  const float* W2 = (const float*)d_in[27]; const float* b2 = (const float*)d_in[28];
  const float* ln3g = (const float*)d_in[29]; const float* ln3b = (const float*)d_in[30];

  char* base = (char*)d_ws;
  bf16*  WqkT   = (bf16*)base;  base += 262144;   // [512][256]
  bf16*  WvT    = (bf16*)base;  base += 131072;
  bf16*  WoT    = (bf16*)base;  base += 131072;
  bf16*  WvalT  = (bf16*)base;  base += 131072;
  bf16*  WdoT   = (bf16*)base;  base += 131072;
  bf16*  W1T    = (bf16*)base;  base += 262144;   // [512][256]
  bf16*  W2T    = (bf16*)base;  base += 262144;   // [256][512]
  bf16*  Woffb  = (bf16*)base;  base += 32768;
  bf16*  Wattnb = (bf16*)base;  base += 16384;
  bf16*  qh_b   = (bf16*)base;  base += 1843200;
  bf16*  kh_b   = (bf16*)base;  base += 1843200;
  bf16*  vt     = (bf16*)base;  base += 1966080;  // [1024][960]
  bf16*  attn_b = (bf16*)base;  base += 1843200;
  float* out2   = (float*)base; base += 3686400;
  float* sampled= (float*)base; base += 3686400;
  bf16*  out4_b = (bf16*)base;  base += 1843200;
  bf16*  hid    = (bf16*)base;  base += 3686400;  // [3600][512] bf16
  float* locb   = (float*)base; base += 921600;
  float* awb    = (float*)base; base += 460800;
  float* lin    = (float*)base; base += 3686400;  // shared pre-LN buffer

  // zero vt pad columns (keys 900..959) so split-K PV never multiplies garbage
  hipMemsetAsync(vt, 0, 1966080, stream);

  cvtAll<<<736, 256, 0, stream>>>(Wq, Wk, Wv, Wo, Wval, Wdo, W1, W2, Woff, Wattn,
                                  WqkT, WvT, WoT, WvalT, WdoT, W1T, W2T, Woffb, Wattnb);
  // fused q,k,v projections
  qkv_mm_kernel<<<dim3(113, 12), 128, 0, stream>>>(queries, og, WqkT, WvT, bq, bk, bv,
                                                   qh_b, kh_b, vt);
  mha_flash<<<dim3(29, HH, NB), 256, 0, stream>>>(qh_b, kh_b, vt, mask, attn_b);
  // Wo GEMM + queries residual -> lin
  mm2_kernel<2,256,2><<<dim3(113,4), 128, 0, stream>>>(attn_b, WoT, bo, queries, nullptr,
                                                       lin, nullptr);
  // LN1 + off/attn GEMV fused (aug stays in LDS)
  ln_off_attn_kernel<<<MT, 128, 0, stream>>>(lin, ln1g, ln1b, og, ref,
                                             Woffb, boff, Wattnb, battn,
                                             out2, locb, awb);
  deform_proj_kernel<<<MT/RPB, 256, 0, stream>>>(bev, locb, awb, WvalT, bval, sampled);
  // Wdo GEMM * mask + out2 residual -> lin
  mm2_kernel<0,256,3><<<dim3(113,4), 128, 0, stream>>>(sampled, WdoT, bdo, out2, mask,
                                                       lin, nullptr);
  ln_kernel<1><<<900, 256, 0, stream>>>(lin, ln2g, ln2b, out4_b);
  // FFN1 + relu -> hid bf16
  mm2_kernel<2,256,4><<<dim3(113,8), 128, 0, stream>>>(out4_b, W1T, b1, nullptr, nullptr,
                                                       hid, nullptr);
  // FFN2 + out4 residual -> lin
  mm2_kernel<2,512,5><<<dim3(113,4), 128, 0, stream>>>(hid, W2T, b2, nullptr, nullptr,
                                                       lin, out4_b);
  ln_kernel<2><<<900, 256, 0, stream>>>(lin, ln3g, ln3b, (float*)d_out);
}